// Round 7
// baseline (311.661 us; speedup 1.0000x reference)
//
#include <hip/hip_runtime.h>
#include <hip/hip_bf16.h>

// GCN 2-layer, CSR aggregation, bf16 intermediates (fp32 accumulation).
// flags[0]=1 if floats bf16 else fp32; flags[1]=1 if edge_index int64 else int32.
// Aggregation kernels use multi-edge-per-wave layout: lane = (edge_group, feature_quad),
// dwordx2 bf16 gathers, shfl_xor reduction across edge groups.

constexpr int D_IN  = 128;
constexpr int D_HID = 64;
constexpr int D_OUT = 16;

constexpr int WSHIFT  = 10;      // bucket = dst >> 10 (1024 nodes/bucket)
constexpr int MAXB    = 128;     // max buckets (n <= 131072)
constexpr int BCAP    = 24576;   // bucket capacity (mean 16384 at E/N=16)
constexpr int BIN_CAP = 96;      // LDS bin cap per bucket per chunk (mean 42)
constexpr int CHUNK   = 4096;

__device__ inline float bflo(unsigned u){ return __uint_as_float(u << 16); }
__device__ inline float bfhi(unsigned u){ return __uint_as_float(u & 0xffff0000u); }
__device__ inline float bfu (unsigned short u){ return __uint_as_float(((unsigned)u) << 16); }
__device__ inline unsigned f2bu(float f){
    __hip_bfloat16 h = __float2bfloat16(f);
    return (unsigned)*reinterpret_cast<unsigned short*>(&h);
}
__device__ inline float sigf(float x){ return 1.0f / (1.0f + __expf(-x)); }

// ---------------- dtype detection + gcur zero ----------------
__global__ void k_detect(const unsigned* __restrict__ xraw,
                         const int* __restrict__ eraw,
                         int* __restrict__ flags, unsigned* __restrict__ gcur)
{
    int t = threadIdx.x;
    if (t < 128) gcur[t] = 0u;
    if (t == 0){
        int bad = 0;
        for (int i = 0; i < 64; ++i){
            unsigned w = xraw[i];
            unsigned h0 = w & 0xffffu, h1 = w >> 16;
            unsigned e0 = (h0 >> 7) & 0xffu, e1 = (h1 >> 7) & 0xffu;
            if (!((h0 & 0x7fffu) == 0 || (e0 >= 97 && e0 <= 157))) ++bad;
            if (!((h1 & 0x7fffu) == 0 || (e1 >= 97 && e1 <= 157))) ++bad;
        }
        flags[0] = (bad > 8) ? 0 : 1;
        int zeroOdd = 0;
        for (int i = 0; i < 64; ++i)
            if (eraw[2 * i + 1] == 0) ++zeroOdd;
        flags[1] = (zeroOdd > 48) ? 1 : 0;
    }
}

// ---------------- phase 1: bucketize edges by dst>>10, packed 4B records ----------------
__global__ __launch_bounds__(256) void k_bucketize(
    const int* __restrict__ ei, const int* __restrict__ flags,
    unsigned* __restrict__ gcur, unsigned* __restrict__ gbuf, int ne, int B)
{
    __shared__ unsigned bcnt[MAXB];
    __shared__ unsigned bbase[MAXB];
    __shared__ unsigned bins[MAXB * BIN_CAP];   // 49.2 KB

    const int t = threadIdx.x, lane = t & 63, wv = t >> 6;
    const int i64 = flags[1];
    const int e0 = blockIdx.x * CHUNK;

    if (t < MAXB) bcnt[t] = 0u;
    __syncthreads();

    for (int k = 0; k < CHUNK / 256; ++k){
        int e = e0 + k * 256 + t;
        if (e < ne){
            int s, d;
            if (i64){ s = ei[2 * e]; d = ei[2 * (ne + e)]; }
            else    { s = ei[e];     d = ei[ne + e]; }
            int b = d >> WSHIFT;
            unsigned v = ((unsigned)s << WSHIFT) | ((unsigned)d & ((1u << WSHIFT) - 1));
            unsigned p = atomicAdd(&bcnt[b], 1u);
            if (p < (unsigned)BIN_CAP){
                bins[b * BIN_CAP + p] = v;
            } else {                                   // rare overflow: direct
                unsigned g = atomicAdd(&gcur[b], 1u);
                gbuf[(size_t)b * BCAP + g] = v;
            }
        }
    }
    __syncthreads();

    if (t < B){
        unsigned c = min(bcnt[t], (unsigned)BIN_CAP);
        bbase[t] = atomicAdd(&gcur[t], c);             // reserve contiguous run
    }
    __syncthreads();

    for (int b = wv; b < B; b += 4){
        unsigned c = min(bcnt[b], (unsigned)BIN_CAP);
        for (unsigned o = lane; o < c; o += 64)
            gbuf[(size_t)b * BCAP + bbase[b] + o] = bins[b * BIN_CAP + o];
    }
}

// ---------------- phase 2: per-bucket hist + scan + csr fill (1024 threads) ----------------
__global__ __launch_bounds__(1024) void k_build(
    const unsigned* __restrict__ gbuf, const unsigned* __restrict__ gcnt,
    unsigned* __restrict__ off, float* __restrict__ dinv, int* __restrict__ csr,
    int n, int B)
{
    __shared__ unsigned hist[1024];
    __shared__ unsigned offl[1024];
    __shared__ unsigned wsums[16];
    __shared__ unsigned gsc[MAXB];
    __shared__ unsigned bb_s;

    const int t = threadIdx.x, lane = t & 63, wv = t >> 6;
    const int b = blockIdx.x;
    const int base = b << WSHIFT;
    const int nodes = min(1024, n - base);

    if (t < B) gsc[t] = gcnt[t];
    hist[t] = 0u;
    __syncthreads();
    if (t == 0){
        unsigned s = 0;
        for (int i = 0; i < b; ++i) s += gsc[i];
        bb_s = s;
    }
    const unsigned cnt = gsc[b];
    const unsigned* mybuf = gbuf + (size_t)b * BCAP;

    for (unsigned i = t; i < cnt; i += 1024)
        atomicAdd(&hist[mybuf[i] & ((1u << WSHIFT) - 1)], 1u);
    __syncthreads();

    // exclusive scan of 1024 counters, one per thread
    unsigned v = hist[t];
    unsigned x = v;
    #pragma unroll
    for (int o = 1; o < 64; o <<= 1){
        unsigned y = __shfl_up(x, o, 64);
        if (lane >= o) x += y;
    }
    if (lane == 63) wsums[wv] = x;
    __syncthreads();
    if (t == 0){
        unsigned run = 0;
        #pragma unroll
        for (int w = 0; w < 16; ++w){ unsigned tv = wsums[w]; wsums[w] = run; run += tv; }
    }
    __syncthreads();
    unsigned exc = x - v + wsums[wv];
    offl[t] = exc;
    __syncthreads();

    const unsigned bb = bb_s;
    if (t < nodes){
        off[base + t] = bb + offl[t];
        dinv[base + t] = rsqrtf(1.0f + (float)v);
    }
    if (b == B - 1 && t == 0) off[n] = bb + cnt;
    __syncthreads();

    hist[t] = offl[t];          // cursors <- local offsets
    __syncthreads();

    for (unsigned i = t; i < cnt; i += 1024){
        unsigned rec = mybuf[i];
        unsigned p = atomicAdd(&hist[rec & ((1u << WSHIFT) - 1)], 1u);
        csr[bb + p] = (int)(rec >> WSHIFT);
    }
}

// ---------------- linear 1: h1(bf16) = x @ W1 ----------------
__global__ __launch_bounds__(256) void k_linear1(
    const unsigned* __restrict__ xraw, const unsigned* __restrict__ w1raw,
    const int* __restrict__ flags, unsigned short* __restrict__ h1b, int n)
{
    __shared__ float w1s[D_IN * D_HID];
    __shared__ float xs[16][132];

    const int isBf16 = flags[0];

    if (isBf16){
        const uint4* wv = (const uint4*)w1raw;
        for (int i = threadIdx.x; i < (D_IN * D_HID) / 8; i += 256){
            uint4 u = wv[i];
            float* o = &w1s[i * 8];
            o[0]=bflo(u.x); o[1]=bfhi(u.x); o[2]=bflo(u.y); o[3]=bfhi(u.y);
            o[4]=bflo(u.z); o[5]=bfhi(u.z); o[6]=bflo(u.w); o[7]=bfhi(u.w);
        }
    } else {
        const float4* wv = (const float4*)w1raw;
        for (int i = threadIdx.x; i < (D_IN * D_HID) / 4; i += 256)
            ((float4*)w1s)[i] = wv[i];
    }

    const int ln = threadIdx.x >> 4;
    const int cg = threadIdx.x & 15;

    for (int nb = blockIdx.x * 16; nb < n; nb += gridDim.x * 16){
        {
            int node = nb + ln;
            float4 a, b;
            if (node >= n){
                a = make_float4(0,0,0,0); b = a;
            } else if (isBf16){
                uint4 u = ((const uint4*)xraw)[(size_t)node * (D_IN / 8) + cg];
                a = make_float4(bflo(u.x), bfhi(u.x), bflo(u.y), bfhi(u.y));
                b = make_float4(bflo(u.z), bfhi(u.z), bflo(u.w), bfhi(u.w));
            } else {
                const float4* xr = (const float4*)xraw;
                a = xr[(size_t)node * (D_IN / 4) + cg * 2];
                b = xr[(size_t)node * (D_IN / 4) + cg * 2 + 1];
            }
            float4* o = (float4*)&xs[ln][cg * 8];
            o[0] = a; o[1] = b;
        }
        __syncthreads();

        int node = nb + ln;
        float a0=0.f, a1=0.f, a2=0.f, a3=0.f;
        #pragma unroll 8
        for (int k = 0; k < D_IN; ++k){
            float xv = xs[ln][k];
            const float* wr = &w1s[k * D_HID + cg * 4];
            a0 = fmaf(xv, wr[0], a0);
            a1 = fmaf(xv, wr[1], a1);
            a2 = fmaf(xv, wr[2], a2);
            a3 = fmaf(xv, wr[3], a3);
        }
        if (node < n){
            uint2 pk;
            pk.x = f2bu(a0) | (f2bu(a1) << 16);
            pk.y = f2bu(a2) | (f2bu(a3) << 16);
            *(uint2*)&h1b[(size_t)node * D_HID + cg * 4] = pk;
        }
        __syncthreads();
    }
}

// ---------------- aggA: wave per dst; lane = (edge_group 0..3, feat_quad 0..15) ----------------
__global__ __launch_bounds__(256) void k_aggA(
    const unsigned* __restrict__ off, const int* __restrict__ csr_src,
    const float* __restrict__ dinv, const unsigned short* __restrict__ h1b,
    const unsigned* __restrict__ b1raw, const int* __restrict__ flags,
    unsigned short* __restrict__ actb, int n)
{
    const int lane = threadIdx.x & 63;
    const int d = blockIdx.x * 4 + (threadIdx.x >> 6);
    if (d >= n) return;
    const int g = lane >> 4;        // edge group
    const int f = lane & 15;        // feature quad: features 4f..4f+3
    const float dd = dinv[d];
    float a0=0.f, a1=0.f, a2=0.f, a3=0.f;
    const int beg = (int)off[d], end = (int)off[d + 1];
    for (int i = beg; i < end; i += 4){
        int e = i + g;
        if (e < end){
            int s = csr_src[e];                 // broadcast across the 16-lane group
            float w = dinv[s] * dd;
            uint2 u = *(const uint2*)&h1b[(size_t)s * D_HID + f * 4];
            a0 = fmaf(bflo(u.x), w, a0);
            a1 = fmaf(bfhi(u.x), w, a1);
            a2 = fmaf(bflo(u.y), w, a2);
            a3 = fmaf(bfhi(u.y), w, a3);
        }
    }
    // reduce 4 edge groups
    #pragma unroll
    for (int o = 16; o < 64; o <<= 1){
        a0 += __shfl_xor(a0, o, 64);
        a1 += __shfl_xor(a1, o, 64);
        a2 += __shfl_xor(a2, o, 64);
        a3 += __shfl_xor(a3, o, 64);
    }
    if (g == 0){
        uint2 su = *(const uint2*)&h1b[(size_t)d * D_HID + f * 4];
        float sl = dd * dd;
        a0 = fmaf(bflo(su.x), sl, a0);
        a1 = fmaf(bfhi(su.x), sl, a1);
        a2 = fmaf(bflo(su.y), sl, a2);
        a3 = fmaf(bfhi(su.y), sl, a3);
        float b0, b1v, b2v, b3v;
        if (flags[0]){
            uint2 bu = ((const uint2*)b1raw)[f];
            b0 = bflo(bu.x); b1v = bfhi(bu.x); b2v = bflo(bu.y); b3v = bfhi(bu.y);
        } else {
            const float4* bp = (const float4*)b1raw;
            float4 bb = bp[f];
            b0 = bb.x; b1v = bb.y; b2v = bb.z; b3v = bb.w;
        }
        uint2 pk;
        pk.x = f2bu(sigf(a0 + b0)) | (f2bu(sigf(a1 + b1v)) << 16);
        pk.y = f2bu(sigf(a2 + b2v)) | (f2bu(sigf(a3 + b3v)) << 16);
        *(uint2*)&actb[(size_t)d * D_HID + f * 4] = pk;
    }
}

// ---------------- linear 2: h2(bf16) = act(bf16) @ W2 ----------------
__global__ __launch_bounds__(256) void k_linear2(
    const unsigned short* __restrict__ actb, const unsigned* __restrict__ w2raw,
    const int* __restrict__ flags, unsigned short* __restrict__ h2b, int n)
{
    __shared__ float w2s[D_HID * D_OUT];
    __shared__ float as[16][68];

    const int isBf16 = flags[0];

    if (isBf16){
        const uint4* wv = (const uint4*)w2raw;
        for (int i = threadIdx.x; i < (D_HID * D_OUT) / 8; i += 256){
            uint4 u = wv[i];
            float* o = &w2s[i * 8];
            o[0]=bflo(u.x); o[1]=bfhi(u.x); o[2]=bflo(u.y); o[3]=bfhi(u.y);
            o[4]=bflo(u.z); o[5]=bfhi(u.z); o[6]=bflo(u.w); o[7]=bfhi(u.w);
        }
    } else {
        const float4* wv = (const float4*)w2raw;
        for (int i = threadIdx.x; i < (D_HID * D_OUT) / 4; i += 256)
            ((float4*)w2s)[i] = wv[i];
    }

    const int ln  = threadIdx.x >> 4;
    const int col = threadIdx.x & 15;

    for (int nb = blockIdx.x * 16; nb < n; nb += gridDim.x * 16){
        {
            int node = nb + ln;
            uint2 u = make_uint2(0u, 0u);
            if (node < n)
                u = *(const uint2*)&actb[(size_t)node * D_HID + col * 4];
            float* o = &as[ln][col * 4];
            o[0] = bflo(u.x); o[1] = bfhi(u.x);
            o[2] = bflo(u.y); o[3] = bfhi(u.y);
        }
        __syncthreads();

        int node = nb + ln;
        float acc = 0.f;
        #pragma unroll 8
        for (int k = 0; k < D_HID; ++k)
            acc = fmaf(as[ln][k], w2s[k * D_OUT + col], acc);

        if (node < n) h2b[(size_t)node * D_OUT + col] = (unsigned short)f2bu(acc);
        __syncthreads();
    }
}

// ---------------- aggB: wave per dst; lane = (edge_group 0..15, feat_quad 0..3) ----------------
__global__ __launch_bounds__(256) void k_aggB(
    const unsigned* __restrict__ off, const int* __restrict__ csr_src,
    const float* __restrict__ dinv, const unsigned short* __restrict__ h2b,
    const unsigned* __restrict__ b2raw, const int* __restrict__ flags,
    void* __restrict__ out, int n)
{
    const int lane = threadIdx.x & 63;
    const int d = blockIdx.x * 4 + (threadIdx.x >> 6);
    const int isBf16 = flags[0];
    if (d >= n) return;
    const int g = lane >> 2;        // edge group 0..15
    const int f = lane & 3;         // feature quad: features 4f..4f+3
    const float dd = dinv[d];
    float a0=0.f, a1=0.f, a2=0.f, a3=0.f;
    const int beg = (int)off[d], end = (int)off[d + 1];
    for (int i = beg; i < end; i += 16){
        int e = i + g;
        if (e < end){
            int s = csr_src[e];
            float w = dinv[s] * dd;
            uint2 u = *(const uint2*)&h2b[(size_t)s * D_OUT + f * 4];
            a0 = fmaf(bflo(u.x), w, a0);
            a1 = fmaf(bfhi(u.x), w, a1);
            a2 = fmaf(bflo(u.y), w, a2);
            a3 = fmaf(bfhi(u.y), w, a3);
        }
    }
    #pragma unroll
    for (int o = 4; o < 64; o <<= 1){
        a0 += __shfl_xor(a0, o, 64);
        a1 += __shfl_xor(a1, o, 64);
        a2 += __shfl_xor(a2, o, 64);
        a3 += __shfl_xor(a3, o, 64);
    }
    if (g == 0){                    // lanes 0..3 hold the 16 outputs
        uint2 su = *(const uint2*)&h2b[(size_t)d * D_OUT + f * 4];
        float sl = dd * dd;
        a0 = fmaf(bflo(su.x), sl, a0);
        a1 = fmaf(bfhi(su.x), sl, a1);
        a2 = fmaf(bflo(su.y), sl, a2);
        a3 = fmaf(bfhi(su.y), sl, a3);
        float b0, b1v, b2v, b3v;
        if (isBf16){
            uint2 bu = ((const uint2*)b2raw)[f];
            b0 = bflo(bu.x); b1v = bfhi(bu.x); b2v = bflo(bu.y); b3v = bfhi(bu.y);
        } else {
            float4 bb = ((const float4*)b2raw)[f];
            b0 = bb.x; b1v = bb.y; b2v = bb.z; b3v = bb.w;
        }
        a0 += b0; a1 += b1v; a2 += b2v; a3 += b3v;
        // log_softmax over 16 values spread across 4 lanes x 4 regs
        float m = fmaxf(fmaxf(a0, a1), fmaxf(a2, a3));
        m = fmaxf(m, __shfl_xor(m, 1, 4));
        m = fmaxf(m, __shfl_xor(m, 2, 4));
        float s = __expf(a0 - m) + __expf(a1 - m) + __expf(a2 - m) + __expf(a3 - m);
        s += __shfl_xor(s, 1, 4);
        s += __shfl_xor(s, 2, 4);
        float ls = m + __logf(s);
        if (isBf16){
            uint2 pk;
            pk.x = f2bu(a0 - ls) | (f2bu(a1 - ls) << 16);
            pk.y = f2bu(a2 - ls) | (f2bu(a3 - ls) << 16);
            *(uint2*)((__hip_bfloat16*)out + (size_t)d * D_OUT + f * 4) = pk;
        } else {
            float4 o4 = make_float4(a0 - ls, a1 - ls, a2 - ls, a3 - ls);
            *(float4*)((float*)out + (size_t)d * D_OUT + f * 4) = o4;
        }
    }
}

extern "C" void kernel_launch(void* const* d_in, const int* in_sizes, int n_in,
                              void* d_out, int out_size, void* d_ws, size_t ws_size,
                              hipStream_t stream)
{
    const unsigned* xraw  = (const unsigned*)d_in[0];
    const int*      ei    = (const int*)d_in[1];
    const unsigned* w1raw = (const unsigned*)d_in[2];
    const unsigned* b1raw = (const unsigned*)d_in[3];
    const unsigned* w2raw = (const unsigned*)d_in[4];
    const unsigned* b2raw = (const unsigned*)d_in[5];

    const int n  = in_sizes[0] / D_IN;   // 100000
    const int ne = in_sizes[1] / 2;      // 1600000
    const int B  = (n + ((1 << WSHIFT) - 1)) >> WSHIFT;   // 98 buckets

    // ws layout (4B words):
    // flags[64] | gcur[128] | dinv[nAl] | off[nAl+64] | csr[neAl] | gbuf[MAXB*BCAP]
    //   | h1b[n*64 bf16] | actb[n*64 bf16] | h2b[n*16 bf16]
    size_t nAl  = ((size_t)n + 255) & ~(size_t)255;
    size_t neAl = ((size_t)ne + 255) & ~(size_t)255;
    int*            flags = (int*)d_ws;
    unsigned*       gcur  = (unsigned*)d_ws + 64;
    float*          dinv  = (float*)(gcur + 128);
    unsigned*       off   = (unsigned*)(dinv + nAl);
    int*            csr   = (int*)(off + nAl + 64);
    unsigned*       gbuf  = (unsigned*)(csr + neAl);
    unsigned short* h1b   = (unsigned short*)(gbuf + (size_t)MAXB * BCAP);
    unsigned short* actb  = h1b + (size_t)n * D_HID;
    unsigned short* h2b   = actb + (size_t)n * D_HID;

    const int nchunk = (ne + CHUNK - 1) / CHUNK;

    k_detect    <<<1, 128, 0, stream>>>(xraw, ei, flags, gcur);
    k_bucketize <<<nchunk, 256, 0, stream>>>(ei, flags, gcur, gbuf, ne, B);
    k_build     <<<B, 1024, 0, stream>>>(gbuf, gcur, off, dinv, csr, n, B);

    k_linear1   <<<768, 256, 0, stream>>>(xraw, w1raw, flags, h1b, n);
    k_aggA      <<<(n + 3) / 4, 256, 0, stream>>>(off, csr, dinv, h1b, b1raw, flags, actb, n);
    k_linear2   <<<768, 256, 0, stream>>>(actb, w2raw, flags, h2b, n);
    k_aggB      <<<(n + 3) / 4, 256, 0, stream>>>(off, csr, dinv, h2b, b2raw, flags, d_out, n);
}

// Round 8
// 246.975 us; speedup vs baseline: 1.2619x; 1.2619x over previous
//
#include <hip/hip_runtime.h>
#include <hip/hip_bf16.h>

// GCN 2-layer, CSR aggregation, bf16 intermediates (fp32 accumulation).
// Key algebraic trick: intermediates stored pre-scaled by dinv (h1s = h1*dinv),
// so per-edge aggregation is pure gather+add: agg[d] = dinv[d]*(sum h1s[nbr] + h1s[d]).
// flags[0]=1 if floats bf16 else fp32; flags[1]=1 if edge_index int64 else int32.

constexpr int D_IN  = 128;
constexpr int D_HID = 64;
constexpr int D_OUT = 16;

constexpr int WSHIFT  = 10;      // bucket = dst >> 10 (1024 nodes/bucket)
constexpr int MAXB    = 128;     // max buckets (n <= 131072)
constexpr int BCAP    = 24576;   // bucket capacity (mean 16384 at E/N=16)
constexpr int BIN_CAP = 96;      // LDS bin cap per bucket per chunk (mean 42)
constexpr int CHUNK   = 4096;

__device__ inline float bflo(unsigned u){ return __uint_as_float(u << 16); }
__device__ inline float bfhi(unsigned u){ return __uint_as_float(u & 0xffff0000u); }
__device__ inline unsigned f2bu(float f){
    __hip_bfloat16 h = __float2bfloat16(f);
    return (unsigned)*reinterpret_cast<unsigned short*>(&h);
}
__device__ inline float sigf(float x){ return 1.0f / (1.0f + __expf(-x)); }

// ---------------- dtype detection + gcur zero ----------------
__global__ void k_detect(const unsigned* __restrict__ xraw,
                         const int* __restrict__ eraw,
                         int* __restrict__ flags, unsigned* __restrict__ gcur)
{
    int t = threadIdx.x;
    if (t < 128) gcur[t] = 0u;
    if (t == 0){
        int bad = 0;
        for (int i = 0; i < 64; ++i){
            unsigned w = xraw[i];
            unsigned h0 = w & 0xffffu, h1 = w >> 16;
            unsigned e0 = (h0 >> 7) & 0xffu, e1 = (h1 >> 7) & 0xffu;
            if (!((h0 & 0x7fffu) == 0 || (e0 >= 97 && e0 <= 157))) ++bad;
            if (!((h1 & 0x7fffu) == 0 || (e1 >= 97 && e1 <= 157))) ++bad;
        }
        flags[0] = (bad > 8) ? 0 : 1;
        int zeroOdd = 0;
        for (int i = 0; i < 64; ++i)
            if (eraw[2 * i + 1] == 0) ++zeroOdd;
        flags[1] = (zeroOdd > 48) ? 1 : 0;
    }
}

// ---------------- phase 1: bucketize edges by dst>>10, packed 4B records ----------------
__global__ __launch_bounds__(256) void k_bucketize(
    const int* __restrict__ ei, const int* __restrict__ flags,
    unsigned* __restrict__ gcur, unsigned* __restrict__ gbuf, int ne, int B)
{
    __shared__ unsigned bcnt[MAXB];
    __shared__ unsigned bbase[MAXB];
    __shared__ unsigned bins[MAXB * BIN_CAP];   // 49.2 KB

    const int t = threadIdx.x, lane = t & 63, wv = t >> 6;
    const int i64 = flags[1];
    const int e0 = blockIdx.x * CHUNK;

    if (t < MAXB) bcnt[t] = 0u;
    __syncthreads();

    for (int k = 0; k < CHUNK / 256; ++k){
        int e = e0 + k * 256 + t;
        if (e < ne){
            int s, d;
            if (i64){ s = ei[2 * e]; d = ei[2 * (ne + e)]; }
            else    { s = ei[e];     d = ei[ne + e]; }
            int b = d >> WSHIFT;
            unsigned v = ((unsigned)s << WSHIFT) | ((unsigned)d & ((1u << WSHIFT) - 1));
            unsigned p = atomicAdd(&bcnt[b], 1u);
            if (p < (unsigned)BIN_CAP){
                bins[b * BIN_CAP + p] = v;
            } else {                                   // rare overflow: direct
                unsigned g = atomicAdd(&gcur[b], 1u);
                gbuf[(size_t)b * BCAP + g] = v;
            }
        }
    }
    __syncthreads();

    if (t < B){
        unsigned c = min(bcnt[t], (unsigned)BIN_CAP);
        bbase[t] = atomicAdd(&gcur[t], c);             // reserve contiguous run
    }
    __syncthreads();

    for (int b = wv; b < B; b += 4){
        unsigned c = min(bcnt[b], (unsigned)BIN_CAP);
        for (unsigned o = lane; o < c; o += 64)
            gbuf[(size_t)b * BCAP + bbase[b] + o] = bins[b * BIN_CAP + o];
    }
}

// ---------------- phase 2: per-bucket hist + scan + csr fill (1024 threads) ----------------
__global__ __launch_bounds__(1024) void k_build(
    const unsigned* __restrict__ gbuf, const unsigned* __restrict__ gcnt,
    unsigned* __restrict__ off, float* __restrict__ dinv, int* __restrict__ csr,
    int n, int B)
{
    __shared__ unsigned hist[1024];
    __shared__ unsigned offl[1024];
    __shared__ unsigned wsums[16];
    __shared__ unsigned gsc[MAXB];
    __shared__ unsigned bb_s;

    const int t = threadIdx.x, lane = t & 63, wv = t >> 6;
    const int b = blockIdx.x;
    const int base = b << WSHIFT;
    const int nodes = min(1024, n - base);

    if (t < B) gsc[t] = gcnt[t];
    hist[t] = 0u;
    __syncthreads();
    if (t == 0){
        unsigned s = 0;
        for (int i = 0; i < b; ++i) s += gsc[i];
        bb_s = s;
    }
    const unsigned cnt = gsc[b];
    const unsigned* mybuf = gbuf + (size_t)b * BCAP;

    for (unsigned i = t; i < cnt; i += 1024)
        atomicAdd(&hist[mybuf[i] & ((1u << WSHIFT) - 1)], 1u);
    __syncthreads();

    unsigned v = hist[t];
    unsigned x = v;
    #pragma unroll
    for (int o = 1; o < 64; o <<= 1){
        unsigned y = __shfl_up(x, o, 64);
        if (lane >= o) x += y;
    }
    if (lane == 63) wsums[wv] = x;
    __syncthreads();
    if (t == 0){
        unsigned run = 0;
        #pragma unroll
        for (int w = 0; w < 16; ++w){ unsigned tv = wsums[w]; wsums[w] = run; run += tv; }
    }
    __syncthreads();
    unsigned exc = x - v + wsums[wv];
    offl[t] = exc;
    __syncthreads();

    const unsigned bb = bb_s;
    if (t < nodes){
        off[base + t] = bb + offl[t];
        dinv[base + t] = rsqrtf(1.0f + (float)v);
    }
    if (b == B - 1 && t == 0) off[n] = bb + cnt;
    __syncthreads();

    hist[t] = offl[t];          // cursors <- local offsets
    __syncthreads();

    for (unsigned i = t; i < cnt; i += 1024){
        unsigned rec = mybuf[i];
        unsigned p = atomicAdd(&hist[rec & ((1u << WSHIFT) - 1)], 1u);
        csr[bb + p] = (int)(rec >> WSHIFT);
    }
}

// ---------------- linear 1: h1s(bf16) = (x @ W1) * dinv[node] ----------------
__global__ __launch_bounds__(256) void k_linear1(
    const unsigned* __restrict__ xraw, const unsigned* __restrict__ w1raw,
    const int* __restrict__ flags, const float* __restrict__ dinv,
    unsigned short* __restrict__ h1s, int n)
{
    __shared__ float w1s[D_IN * D_HID];
    __shared__ float xs[16][132];

    const int isBf16 = flags[0];

    if (isBf16){
        const uint4* wv = (const uint4*)w1raw;
        for (int i = threadIdx.x; i < (D_IN * D_HID) / 8; i += 256){
            uint4 u = wv[i];
            float* o = &w1s[i * 8];
            o[0]=bflo(u.x); o[1]=bfhi(u.x); o[2]=bflo(u.y); o[3]=bfhi(u.y);
            o[4]=bflo(u.z); o[5]=bfhi(u.z); o[6]=bflo(u.w); o[7]=bfhi(u.w);
        }
    } else {
        const float4* wv = (const float4*)w1raw;
        for (int i = threadIdx.x; i < (D_IN * D_HID) / 4; i += 256)
            ((float4*)w1s)[i] = wv[i];
    }

    const int ln = threadIdx.x >> 4;
    const int cg = threadIdx.x & 15;

    for (int nb = blockIdx.x * 16; nb < n; nb += gridDim.x * 16){
        {
            int node = nb + ln;
            float4 a, b;
            if (node >= n){
                a = make_float4(0,0,0,0); b = a;
            } else if (isBf16){
                uint4 u = ((const uint4*)xraw)[(size_t)node * (D_IN / 8) + cg];
                a = make_float4(bflo(u.x), bfhi(u.x), bflo(u.y), bfhi(u.y));
                b = make_float4(bflo(u.z), bfhi(u.z), bflo(u.w), bfhi(u.w));
            } else {
                const float4* xr = (const float4*)xraw;
                a = xr[(size_t)node * (D_IN / 4) + cg * 2];
                b = xr[(size_t)node * (D_IN / 4) + cg * 2 + 1];
            }
            float4* o = (float4*)&xs[ln][cg * 8];
            o[0] = a; o[1] = b;
        }
        __syncthreads();

        int node = nb + ln;
        float a0=0.f, a1=0.f, a2=0.f, a3=0.f;
        #pragma unroll 8
        for (int k = 0; k < D_IN; ++k){
            float xv = xs[ln][k];
            const float* wr = &w1s[k * D_HID + cg * 4];
            a0 = fmaf(xv, wr[0], a0);
            a1 = fmaf(xv, wr[1], a1);
            a2 = fmaf(xv, wr[2], a2);
            a3 = fmaf(xv, wr[3], a3);
        }
        if (node < n){
            float di = dinv[node];
            uint2 pk;
            pk.x = f2bu(a0 * di) | (f2bu(a1 * di) << 16);
            pk.y = f2bu(a2 * di) | (f2bu(a3 * di) << 16);
            *(uint2*)&h1s[(size_t)node * D_HID + cg * 4] = pk;
        }
        __syncthreads();
    }
}

// ---------------- aggA: 4 dst/wave, 16 lanes/dst, uint2 gathers, unroll x4 ----------------
__global__ __launch_bounds__(256) void k_aggA(
    const unsigned* __restrict__ off, const int* __restrict__ csr_src,
    const float* __restrict__ dinv, const unsigned short* __restrict__ h1s,
    const unsigned* __restrict__ b1raw, const int* __restrict__ flags,
    unsigned short* __restrict__ actb, int n)
{
    const int lane = threadIdx.x & 63;
    const int wv   = threadIdx.x >> 6;
    const int grp  = lane >> 4;            // dst within wave (0..3)
    const int f    = lane & 15;            // uint2 index within 64-feature row
    const int d    = (blockIdx.x * 4 + wv) * 4 + grp;
    if (d >= n) return;

    const int beg = (int)off[d], end = (int)off[d + 1];
    float a0=0.f, a1=0.f, a2=0.f, a3=0.f;
    int i = beg;
    for (; i + 4 <= end; i += 4){
        int s0 = csr_src[i], s1 = csr_src[i+1], s2 = csr_src[i+2], s3 = csr_src[i+3];
        uint2 u0 = *(const uint2*)&h1s[(size_t)s0 * D_HID + f * 4];
        uint2 u1 = *(const uint2*)&h1s[(size_t)s1 * D_HID + f * 4];
        uint2 u2 = *(const uint2*)&h1s[(size_t)s2 * D_HID + f * 4];
        uint2 u3 = *(const uint2*)&h1s[(size_t)s3 * D_HID + f * 4];
        a0 += bflo(u0.x) + bflo(u1.x) + bflo(u2.x) + bflo(u3.x);
        a1 += bfhi(u0.x) + bfhi(u1.x) + bfhi(u2.x) + bfhi(u3.x);
        a2 += bflo(u0.y) + bflo(u1.y) + bflo(u2.y) + bflo(u3.y);
        a3 += bfhi(u0.y) + bfhi(u1.y) + bfhi(u2.y) + bfhi(u3.y);
    }
    for (; i < end; ++i){
        int s = csr_src[i];
        uint2 u = *(const uint2*)&h1s[(size_t)s * D_HID + f * 4];
        a0 += bflo(u.x); a1 += bfhi(u.x);
        a2 += bflo(u.y); a3 += bfhi(u.y);
    }
    // self loop + dinv[d] scale + bias + sigmoid
    uint2 su = *(const uint2*)&h1s[(size_t)d * D_HID + f * 4];
    a0 += bflo(su.x); a1 += bfhi(su.x);
    a2 += bflo(su.y); a3 += bfhi(su.y);
    const float dd = dinv[d];
    float b0, b1v, b2v, b3v;
    if (flags[0]){
        uint2 bu = ((const uint2*)b1raw)[f];
        b0 = bflo(bu.x); b1v = bfhi(bu.x); b2v = bflo(bu.y); b3v = bfhi(bu.y);
    } else {
        float4 bb = ((const float4*)b1raw)[f];
        b0 = bb.x; b1v = bb.y; b2v = bb.z; b3v = bb.w;
    }
    uint2 pk;
    pk.x = f2bu(sigf(fmaf(a0, dd, b0))) | (f2bu(sigf(fmaf(a1, dd, b1v))) << 16);
    pk.y = f2bu(sigf(fmaf(a2, dd, b2v))) | (f2bu(sigf(fmaf(a3, dd, b3v))) << 16);
    *(uint2*)&actb[(size_t)d * D_HID + f * 4] = pk;
}

// ---------------- linear 2: h2s(bf16) = (act @ W2) * dinv[node] ----------------
__global__ __launch_bounds__(256) void k_linear2(
    const unsigned short* __restrict__ actb, const unsigned* __restrict__ w2raw,
    const int* __restrict__ flags, const float* __restrict__ dinv,
    unsigned short* __restrict__ h2s, int n)
{
    __shared__ float w2s[D_HID * D_OUT];
    __shared__ float as[16][68];

    const int isBf16 = flags[0];

    if (isBf16){
        const uint4* wv = (const uint4*)w2raw;
        for (int i = threadIdx.x; i < (D_HID * D_OUT) / 8; i += 256){
            uint4 u = wv[i];
            float* o = &w2s[i * 8];
            o[0]=bflo(u.x); o[1]=bfhi(u.x); o[2]=bflo(u.y); o[3]=bfhi(u.y);
            o[4]=bflo(u.z); o[5]=bfhi(u.z); o[6]=bflo(u.w); o[7]=bfhi(u.w);
        }
    } else {
        const float4* wv = (const float4*)w2raw;
        for (int i = threadIdx.x; i < (D_HID * D_OUT) / 4; i += 256)
            ((float4*)w2s)[i] = wv[i];
    }

    const int ln  = threadIdx.x >> 4;
    const int col = threadIdx.x & 15;

    for (int nb = blockIdx.x * 16; nb < n; nb += gridDim.x * 16){
        {
            int node = nb + ln;
            uint2 u = make_uint2(0u, 0u);
            if (node < n)
                u = *(const uint2*)&actb[(size_t)node * D_HID + col * 4];
            float* o = &as[ln][col * 4];
            o[0] = bflo(u.x); o[1] = bfhi(u.x);
            o[2] = bflo(u.y); o[3] = bfhi(u.y);
        }
        __syncthreads();

        int node = nb + ln;
        float acc = 0.f;
        #pragma unroll 8
        for (int k = 0; k < D_HID; ++k)
            acc = fmaf(as[ln][k], w2s[k * D_OUT + col], acc);

        if (node < n)
            h2s[(size_t)node * D_OUT + col] = (unsigned short)f2bu(acc * dinv[node]);
        __syncthreads();
    }
}

// ---------------- aggB: 16 dst/wave, 4 lanes/dst, uint2 gathers, unroll x4 ----------------
__global__ __launch_bounds__(256) void k_aggB(
    const unsigned* __restrict__ off, const int* __restrict__ csr_src,
    const float* __restrict__ dinv, const unsigned short* __restrict__ h2s,
    const unsigned* __restrict__ b2raw, const int* __restrict__ flags,
    void* __restrict__ out, int n)
{
    const int lane = threadIdx.x & 63;
    const int wv   = threadIdx.x >> 6;
    const int grp  = lane >> 2;            // dst within wave (0..15)
    const int f    = lane & 3;             // uint2 index within 16-feature row
    const int d    = (blockIdx.x * 4 + wv) * 16 + grp;
    const int isBf16 = flags[0];
    if (d >= n) return;

    const int beg = (int)off[d], end = (int)off[d + 1];
    float a0=0.f, a1=0.f, a2=0.f, a3=0.f;
    int i = beg;
    for (; i + 4 <= end; i += 4){
        int s0 = csr_src[i], s1 = csr_src[i+1], s2 = csr_src[i+2], s3 = csr_src[i+3];
        uint2 u0 = *(const uint2*)&h2s[(size_t)s0 * D_OUT + f * 4];
        uint2 u1 = *(const uint2*)&h2s[(size_t)s1 * D_OUT + f * 4];
        uint2 u2 = *(const uint2*)&h2s[(size_t)s2 * D_OUT + f * 4];
        uint2 u3 = *(const uint2*)&h2s[(size_t)s3 * D_OUT + f * 4];
        a0 += bflo(u0.x) + bflo(u1.x) + bflo(u2.x) + bflo(u3.x);
        a1 += bfhi(u0.x) + bfhi(u1.x) + bfhi(u2.x) + bfhi(u3.x);
        a2 += bflo(u0.y) + bflo(u1.y) + bflo(u2.y) + bflo(u3.y);
        a3 += bfhi(u0.y) + bfhi(u1.y) + bfhi(u2.y) + bfhi(u3.y);
    }
    for (; i < end; ++i){
        int s = csr_src[i];
        uint2 u = *(const uint2*)&h2s[(size_t)s * D_OUT + f * 4];
        a0 += bflo(u.x); a1 += bfhi(u.x);
        a2 += bflo(u.y); a3 += bfhi(u.y);
    }
    uint2 su = *(const uint2*)&h2s[(size_t)d * D_OUT + f * 4];
    a0 += bflo(su.x); a1 += bfhi(su.x);
    a2 += bflo(su.y); a3 += bfhi(su.y);
    const float dd = dinv[d];
    float b0, b1v, b2v, b3v;
    if (isBf16){
        uint2 bu = ((const uint2*)b2raw)[f];
        b0 = bflo(bu.x); b1v = bfhi(bu.x); b2v = bflo(bu.y); b3v = bfhi(bu.y);
    } else {
        float4 bb = ((const float4*)b2raw)[f];
        b0 = bb.x; b1v = bb.y; b2v = bb.z; b3v = bb.w;
    }
    a0 = fmaf(a0, dd, b0); a1 = fmaf(a1, dd, b1v);
    a2 = fmaf(a2, dd, b2v); a3 = fmaf(a3, dd, b3v);
    // log_softmax over 16 values spread across 4 lanes x 4 regs
    float m = fmaxf(fmaxf(a0, a1), fmaxf(a2, a3));
    m = fmaxf(m, __shfl_xor(m, 1, 4));
    m = fmaxf(m, __shfl_xor(m, 2, 4));
    float s = __expf(a0 - m) + __expf(a1 - m) + __expf(a2 - m) + __expf(a3 - m);
    s += __shfl_xor(s, 1, 4);
    s += __shfl_xor(s, 2, 4);
    float ls = m + __logf(s);
    if (isBf16){
        uint2 pk;
        pk.x = f2bu(a0 - ls) | (f2bu(a1 - ls) << 16);
        pk.y = f2bu(a2 - ls) | (f2bu(a3 - ls) << 16);
        *(uint2*)((__hip_bfloat16*)out + (size_t)d * D_OUT + f * 4) = pk;
    } else {
        float4 o4 = make_float4(a0 - ls, a1 - ls, a2 - ls, a3 - ls);
        *(float4*)((float*)out + (size_t)d * D_OUT + f * 4) = o4;
    }
}

extern "C" void kernel_launch(void* const* d_in, const int* in_sizes, int n_in,
                              void* d_out, int out_size, void* d_ws, size_t ws_size,
                              hipStream_t stream)
{
    const unsigned* xraw  = (const unsigned*)d_in[0];
    const int*      ei    = (const int*)d_in[1];
    const unsigned* w1raw = (const unsigned*)d_in[2];
    const unsigned* b1raw = (const unsigned*)d_in[3];
    const unsigned* w2raw = (const unsigned*)d_in[4];
    const unsigned* b2raw = (const unsigned*)d_in[5];

    const int n  = in_sizes[0] / D_IN;   // 100000
    const int ne = in_sizes[1] / 2;      // 1600000
    const int B  = (n + ((1 << WSHIFT) - 1)) >> WSHIFT;   // 98 buckets

    // ws layout (4B words):
    // flags[64] | gcur[128] | dinv[nAl] | off[nAl+64] | csr[neAl] | gbuf[MAXB*BCAP]
    //   | h1s[n*64 bf16] | actb[n*64 bf16] | h2s[n*16 bf16]
    size_t nAl  = ((size_t)n + 255) & ~(size_t)255;
    size_t neAl = ((size_t)ne + 255) & ~(size_t)255;
    int*            flags = (int*)d_ws;
    unsigned*       gcur  = (unsigned*)d_ws + 64;
    float*          dinv  = (float*)(gcur + 128);
    unsigned*       off   = (unsigned*)(dinv + nAl);
    int*            csr   = (int*)(off + nAl + 64);
    unsigned*       gbuf  = (unsigned*)(csr + neAl);
    unsigned short* h1s   = (unsigned short*)(gbuf + (size_t)MAXB * BCAP);
    unsigned short* actb  = h1s + (size_t)n * D_HID;
    unsigned short* h2s   = actb + (size_t)n * D_HID;

    const int nchunk = (ne + CHUNK - 1) / CHUNK;

    k_detect    <<<1, 128, 0, stream>>>(xraw, ei, flags, gcur);
    k_bucketize <<<nchunk, 256, 0, stream>>>(ei, flags, gcur, gbuf, ne, B);
    k_build     <<<B, 1024, 0, stream>>>(gbuf, gcur, off, dinv, csr, n, B);

    k_linear1   <<<768, 256, 0, stream>>>(xraw, w1raw, flags, dinv, h1s, n);
    k_aggA      <<<(n + 15) / 16, 256, 0, stream>>>(off, csr, dinv, h1s, b1raw, flags, actb, n);
    k_linear2   <<<768, 256, 0, stream>>>(actb, w2raw, flags, dinv, h2s, n);
    k_aggB      <<<(n + 63) / 64, 256, 0, stream>>>(off, csr, dinv, h2s, b2raw, flags, d_out, n);
}

// Round 9
// 225.392 us; speedup vs baseline: 1.3828x; 1.0958x over previous
//
#include <hip/hip_runtime.h>
#include <hip/hip_bf16.h>

// GCN 2-layer. CSR aggregation with pre-scaled bf16 intermediates (h1s = h1*dinv),
// MFMA-based linear layers (16x16x32 bf16, weights held in registers, no LDS).
// flags[0]=1 if floats bf16 else fp32; flags[1]=1 if edge_index int64 else int32.

constexpr int D_IN  = 128;
constexpr int D_HID = 64;
constexpr int D_OUT = 16;

constexpr int WSHIFT  = 10;      // bucket = dst >> 10 (1024 nodes/bucket)
constexpr int MAXB    = 128;     // max buckets (n <= 131072)
constexpr int BCAP    = 24576;   // bucket capacity (mean 16384 at E/N=16)
constexpr int BIN_CAP = 96;      // LDS bin cap per bucket per chunk (mean 42)
constexpr int CHUNK   = 4096;

typedef __attribute__((ext_vector_type(8))) short bf16x8;
typedef __attribute__((ext_vector_type(4))) float f32x4;

__device__ inline float bflo(unsigned u){ return __uint_as_float(u << 16); }
__device__ inline float bfhi(unsigned u){ return __uint_as_float(u & 0xffff0000u); }
__device__ inline unsigned f2bu(float f){
    __hip_bfloat16 h = __float2bfloat16(f);
    return (unsigned)*reinterpret_cast<unsigned short*>(&h);
}
__device__ inline float sigf(float x){ return 1.0f / (1.0f + __expf(-x)); }

// ---------------- dtype detection + gcur zero ----------------
__global__ void k_detect(const unsigned* __restrict__ xraw,
                         const int* __restrict__ eraw,
                         int* __restrict__ flags, unsigned* __restrict__ gcur)
{
    int t = threadIdx.x;
    if (t < 128) gcur[t] = 0u;
    if (t == 0){
        int bad = 0;
        for (int i = 0; i < 64; ++i){
            unsigned w = xraw[i];
            unsigned h0 = w & 0xffffu, h1 = w >> 16;
            unsigned e0 = (h0 >> 7) & 0xffu, e1 = (h1 >> 7) & 0xffu;
            if (!((h0 & 0x7fffu) == 0 || (e0 >= 97 && e0 <= 157))) ++bad;
            if (!((h1 & 0x7fffu) == 0 || (e1 >= 97 && e1 <= 157))) ++bad;
        }
        flags[0] = (bad > 8) ? 0 : 1;
        int zeroOdd = 0;
        for (int i = 0; i < 64; ++i)
            if (eraw[2 * i + 1] == 0) ++zeroOdd;
        flags[1] = (zeroOdd > 48) ? 1 : 0;
    }
}

// ---------------- phase 1: bucketize edges by dst>>10, packed 4B records ----------------
__global__ __launch_bounds__(256) void k_bucketize(
    const int* __restrict__ ei, const int* __restrict__ flags,
    unsigned* __restrict__ gcur, unsigned* __restrict__ gbuf, int ne, int B)
{
    __shared__ unsigned bcnt[MAXB];
    __shared__ unsigned bbase[MAXB];
    __shared__ unsigned bins[MAXB * BIN_CAP];   // 49.2 KB

    const int t = threadIdx.x, lane = t & 63, wv = t >> 6;
    const int i64 = flags[1];
    const int e0 = blockIdx.x * CHUNK;

    if (t < MAXB) bcnt[t] = 0u;
    __syncthreads();

    for (int k = 0; k < CHUNK / 256; ++k){
        int e = e0 + k * 256 + t;
        if (e < ne){
            int s, d;
            if (i64){ s = ei[2 * e]; d = ei[2 * (ne + e)]; }
            else    { s = ei[e];     d = ei[ne + e]; }
            int b = d >> WSHIFT;
            unsigned v = ((unsigned)s << WSHIFT) | ((unsigned)d & ((1u << WSHIFT) - 1));
            unsigned p = atomicAdd(&bcnt[b], 1u);
            if (p < (unsigned)BIN_CAP){
                bins[b * BIN_CAP + p] = v;
            } else {                                   // rare overflow: direct
                unsigned g = atomicAdd(&gcur[b], 1u);
                gbuf[(size_t)b * BCAP + g] = v;
            }
        }
    }
    __syncthreads();

    if (t < B){
        unsigned c = min(bcnt[t], (unsigned)BIN_CAP);
        bbase[t] = atomicAdd(&gcur[t], c);             // reserve contiguous run
    }
    __syncthreads();

    for (int b = wv; b < B; b += 4){
        unsigned c = min(bcnt[b], (unsigned)BIN_CAP);
        for (unsigned o = lane; o < c; o += 64)
            gbuf[(size_t)b * BCAP + bbase[b] + o] = bins[b * BIN_CAP + o];
    }
}

// ---------------- phase 2: per-bucket hist + scan + csr fill (1024 threads) ----------------
__global__ __launch_bounds__(1024) void k_build(
    const unsigned* __restrict__ gbuf, const unsigned* __restrict__ gcnt,
    unsigned* __restrict__ off, float* __restrict__ dinv, int* __restrict__ csr,
    int n, int B)
{
    __shared__ unsigned hist[1024];
    __shared__ unsigned offl[1024];
    __shared__ unsigned wsums[16];
    __shared__ unsigned gsc[MAXB];
    __shared__ unsigned bb_s;

    const int t = threadIdx.x, lane = t & 63, wv = t >> 6;
    const int b = blockIdx.x;
    const int base = b << WSHIFT;
    const int nodes = min(1024, n - base);

    if (t < B) gsc[t] = gcnt[t];
    hist[t] = 0u;
    __syncthreads();
    if (t == 0){
        unsigned s = 0;
        for (int i = 0; i < b; ++i) s += gsc[i];
        bb_s = s;
    }
    const unsigned cnt = gsc[b];
    const unsigned* mybuf = gbuf + (size_t)b * BCAP;

    for (unsigned i = t; i < cnt; i += 1024)
        atomicAdd(&hist[mybuf[i] & ((1u << WSHIFT) - 1)], 1u);
    __syncthreads();

    unsigned v = hist[t];
    unsigned x = v;
    #pragma unroll
    for (int o = 1; o < 64; o <<= 1){
        unsigned y = __shfl_up(x, o, 64);
        if (lane >= o) x += y;
    }
    if (lane == 63) wsums[wv] = x;
    __syncthreads();
    if (t == 0){
        unsigned run = 0;
        #pragma unroll
        for (int w = 0; w < 16; ++w){ unsigned tv = wsums[w]; wsums[w] = run; run += tv; }
    }
    __syncthreads();
    unsigned exc = x - v + wsums[wv];
    offl[t] = exc;
    __syncthreads();

    const unsigned bb = bb_s;
    if (t < nodes){
        off[base + t] = bb + offl[t];
        dinv[base + t] = rsqrtf(1.0f + (float)v);
    }
    if (b == B - 1 && t == 0) off[n] = bb + cnt;
    __syncthreads();

    hist[t] = offl[t];          // cursors <- local offsets
    __syncthreads();

    for (unsigned i = t; i < cnt; i += 1024){
        unsigned rec = mybuf[i];
        unsigned p = atomicAdd(&hist[rec & ((1u << WSHIFT) - 1)], 1u);
        csr[bb + p] = (int)(rec >> WSHIFT);
    }
}

// ---------------- linear 1 (MFMA): h1s(bf16) = (x @ W1) * dinv[node] ----------------
// Wave = 16-node tile. B-frags (W1) in registers: [kchunk 0..3][coltile 0..3].
// A[m=lane&15][k=(lane>>4)*8+j]; B[n=lane&15][same k]; C col=lane&15,row=(lane>>4)*4+reg.
__global__ __launch_bounds__(256) void k_linear1(
    const unsigned* __restrict__ xraw, const unsigned* __restrict__ w1raw,
    const int* __restrict__ flags, const float* __restrict__ dinv,
    unsigned short* __restrict__ h1s, int n)
{
    const int lane = threadIdx.x & 63;
    const int wv   = threadIdx.x >> 6;
    const int m = lane & 15, q = lane >> 4;
    const int isBf16 = flags[0];

    bf16x8 bfr[4][4];
    if (isBf16){
        const unsigned short* w = (const unsigned short*)w1raw;
        #pragma unroll
        for (int kc = 0; kc < 4; ++kc)
            #pragma unroll
            for (int ct = 0; ct < 4; ++ct)
                #pragma unroll
                for (int j = 0; j < 8; ++j)
                    bfr[kc][ct][j] = (short)w[(kc*32 + q*8 + j) * D_HID + ct*16 + m];
    } else {
        const float* w = (const float*)w1raw;
        #pragma unroll
        for (int kc = 0; kc < 4; ++kc)
            #pragma unroll
            for (int ct = 0; ct < 4; ++ct)
                #pragma unroll
                for (int j = 0; j < 8; ++j)
                    bfr[kc][ct][j] = (short)f2bu(w[(kc*32 + q*8 + j) * D_HID + ct*16 + m]);
    }

    const int ntiles = (n + 15) >> 4;
    for (int tile = blockIdx.x * 4 + wv; tile < ntiles; tile += gridDim.x * 4){
        const int node0 = tile << 4;
        int arow = node0 + m; if (arow >= n) arow = n - 1;
        f32x4 ac0 = {0,0,0,0}, ac1 = {0,0,0,0}, ac2 = {0,0,0,0}, ac3 = {0,0,0,0};
        #pragma unroll
        for (int kc = 0; kc < 4; ++kc){
            bf16x8 a;
            if (isBf16){
                uint4 u = *(const uint4*)((const unsigned short*)xraw + (size_t)arow * D_IN + kc*32 + q*8);
                a = *reinterpret_cast<bf16x8*>(&u);
            } else {
                const float* xp = (const float*)xraw + (size_t)arow * D_IN + kc*32 + q*8;
                float4 f0 = *(const float4*)xp;
                float4 f1 = *(const float4*)(xp + 4);
                a[0]=(short)f2bu(f0.x); a[1]=(short)f2bu(f0.y); a[2]=(short)f2bu(f0.z); a[3]=(short)f2bu(f0.w);
                a[4]=(short)f2bu(f1.x); a[5]=(short)f2bu(f1.y); a[6]=(short)f2bu(f1.z); a[7]=(short)f2bu(f1.w);
            }
            ac0 = __builtin_amdgcn_mfma_f32_16x16x32_bf16(a, bfr[kc][0], ac0, 0, 0, 0);
            ac1 = __builtin_amdgcn_mfma_f32_16x16x32_bf16(a, bfr[kc][1], ac1, 0, 0, 0);
            ac2 = __builtin_amdgcn_mfma_f32_16x16x32_bf16(a, bfr[kc][2], ac2, 0, 0, 0);
            ac3 = __builtin_amdgcn_mfma_f32_16x16x32_bf16(a, bfr[kc][3], ac3, 0, 0, 0);
        }
        #pragma unroll
        for (int i = 0; i < 4; ++i){
            int nr = node0 + q*4 + i;
            if (nr < n){
                float di = dinv[nr];
                unsigned short* o = h1s + (size_t)nr * D_HID + m;
                o[0]  = (unsigned short)f2bu(ac0[i] * di);
                o[16] = (unsigned short)f2bu(ac1[i] * di);
                o[32] = (unsigned short)f2bu(ac2[i] * di);
                o[48] = (unsigned short)f2bu(ac3[i] * di);
            }
        }
    }
}

// ---------------- aggA: 4 dst/wave, 16 lanes/dst, uint2 gathers, unroll x4 ----------------
__global__ __launch_bounds__(256) void k_aggA(
    const unsigned* __restrict__ off, const int* __restrict__ csr_src,
    const float* __restrict__ dinv, const unsigned short* __restrict__ h1s,
    const unsigned* __restrict__ b1raw, const int* __restrict__ flags,
    unsigned short* __restrict__ actb, int n)
{
    const int lane = threadIdx.x & 63;
    const int wv   = threadIdx.x >> 6;
    const int grp  = lane >> 4;            // dst within wave (0..3)
    const int f    = lane & 15;            // uint2 index within 64-feature row
    const int d    = (blockIdx.x * 4 + wv) * 4 + grp;
    if (d >= n) return;

    const int beg = (int)off[d], end = (int)off[d + 1];
    float a0=0.f, a1=0.f, a2=0.f, a3=0.f;
    int i = beg;
    for (; i + 4 <= end; i += 4){
        int s0 = csr_src[i], s1 = csr_src[i+1], s2 = csr_src[i+2], s3 = csr_src[i+3];
        uint2 u0 = *(const uint2*)&h1s[(size_t)s0 * D_HID + f * 4];
        uint2 u1 = *(const uint2*)&h1s[(size_t)s1 * D_HID + f * 4];
        uint2 u2 = *(const uint2*)&h1s[(size_t)s2 * D_HID + f * 4];
        uint2 u3 = *(const uint2*)&h1s[(size_t)s3 * D_HID + f * 4];
        a0 += bflo(u0.x) + bflo(u1.x) + bflo(u2.x) + bflo(u3.x);
        a1 += bfhi(u0.x) + bfhi(u1.x) + bfhi(u2.x) + bfhi(u3.x);
        a2 += bflo(u0.y) + bflo(u1.y) + bflo(u2.y) + bflo(u3.y);
        a3 += bfhi(u0.y) + bfhi(u1.y) + bfhi(u2.y) + bfhi(u3.y);
    }
    for (; i < end; ++i){
        int s = csr_src[i];
        uint2 u = *(const uint2*)&h1s[(size_t)s * D_HID + f * 4];
        a0 += bflo(u.x); a1 += bfhi(u.x);
        a2 += bflo(u.y); a3 += bfhi(u.y);
    }
    // self loop + dinv[d] scale + bias + sigmoid
    uint2 su = *(const uint2*)&h1s[(size_t)d * D_HID + f * 4];
    a0 += bflo(su.x); a1 += bfhi(su.x);
    a2 += bflo(su.y); a3 += bfhi(su.y);
    const float dd = dinv[d];
    float b0, b1v, b2v, b3v;
    if (flags[0]){
        uint2 bu = ((const uint2*)b1raw)[f];
        b0 = bflo(bu.x); b1v = bfhi(bu.x); b2v = bflo(bu.y); b3v = bfhi(bu.y);
    } else {
        float4 bb = ((const float4*)b1raw)[f];
        b0 = bb.x; b1v = bb.y; b2v = bb.z; b3v = bb.w;
    }
    uint2 pk;
    pk.x = f2bu(sigf(fmaf(a0, dd, b0))) | (f2bu(sigf(fmaf(a1, dd, b1v))) << 16);
    pk.y = f2bu(sigf(fmaf(a2, dd, b2v))) | (f2bu(sigf(fmaf(a3, dd, b3v))) << 16);
    *(uint2*)&actb[(size_t)d * D_HID + f * 4] = pk;
}

// ---------------- linear 2 (MFMA): h2s(bf16) = (act @ W2) * dinv[node] ----------------
__global__ __launch_bounds__(256) void k_linear2(
    const unsigned short* __restrict__ actb, const unsigned* __restrict__ w2raw,
    const int* __restrict__ flags, const float* __restrict__ dinv,
    unsigned short* __restrict__ h2s, int n)
{
    const int lane = threadIdx.x & 63;
    const int wv   = threadIdx.x >> 6;
    const int m = lane & 15, q = lane >> 4;
    const int isBf16 = flags[0];

    bf16x8 bfr[2];
    if (isBf16){
        const unsigned short* w = (const unsigned short*)w2raw;
        #pragma unroll
        for (int kc = 0; kc < 2; ++kc)
            #pragma unroll
            for (int j = 0; j < 8; ++j)
                bfr[kc][j] = (short)w[(kc*32 + q*8 + j) * D_OUT + m];
    } else {
        const float* w = (const float*)w2raw;
        #pragma unroll
        for (int kc = 0; kc < 2; ++kc)
            #pragma unroll
            for (int j = 0; j < 8; ++j)
                bfr[kc][j] = (short)f2bu(w[(kc*32 + q*8 + j) * D_OUT + m]);
    }

    const int ntiles = (n + 15) >> 4;
    for (int tile = blockIdx.x * 4 + wv; tile < ntiles; tile += gridDim.x * 4){
        const int node0 = tile << 4;
        int arow = node0 + m; if (arow >= n) arow = n - 1;
        f32x4 acc = {0,0,0,0};
        #pragma unroll
        for (int kc = 0; kc < 2; ++kc){
            uint4 u = *(const uint4*)(actb + (size_t)arow * D_HID + kc*32 + q*8);
            bf16x8 a = *reinterpret_cast<bf16x8*>(&u);
            acc = __builtin_amdgcn_mfma_f32_16x16x32_bf16(a, bfr[kc], acc, 0, 0, 0);
        }
        #pragma unroll
        for (int i = 0; i < 4; ++i){
            int nr = node0 + q*4 + i;
            if (nr < n)
                h2s[(size_t)nr * D_OUT + m] = (unsigned short)f2bu(acc[i] * dinv[nr]);
        }
    }
}

// ---------------- aggB: 16 dst/wave, 4 lanes/dst, uint2 gathers, unroll x4 ----------------
__global__ __launch_bounds__(256) void k_aggB(
    const unsigned* __restrict__ off, const int* __restrict__ csr_src,
    const float* __restrict__ dinv, const unsigned short* __restrict__ h2s,
    const unsigned* __restrict__ b2raw, const int* __restrict__ flags,
    void* __restrict__ out, int n)
{
    const int lane = threadIdx.x & 63;
    const int wv   = threadIdx.x >> 6;
    const int grp  = lane >> 2;            // dst within wave (0..15)
    const int f    = lane & 3;             // uint2 index within 16-feature row
    const int d    = (blockIdx.x * 4 + wv) * 16 + grp;
    const int isBf16 = flags[0];
    if (d >= n) return;

    const int beg = (int)off[d], end = (int)off[d + 1];
    float a0=0.f, a1=0.f, a2=0.f, a3=0.f;
    int i = beg;
    for (; i + 4 <= end; i += 4){
        int s0 = csr_src[i], s1 = csr_src[i+1], s2 = csr_src[i+2], s3 = csr_src[i+3];
        uint2 u0 = *(const uint2*)&h2s[(size_t)s0 * D_OUT + f * 4];
        uint2 u1 = *(const uint2*)&h2s[(size_t)s1 * D_OUT + f * 4];
        uint2 u2 = *(const uint2*)&h2s[(size_t)s2 * D_OUT + f * 4];
        uint2 u3 = *(const uint2*)&h2s[(size_t)s3 * D_OUT + f * 4];
        a0 += bflo(u0.x) + bflo(u1.x) + bflo(u2.x) + bflo(u3.x);
        a1 += bfhi(u0.x) + bfhi(u1.x) + bfhi(u2.x) + bfhi(u3.x);
        a2 += bflo(u0.y) + bflo(u1.y) + bflo(u2.y) + bflo(u3.y);
        a3 += bfhi(u0.y) + bfhi(u1.y) + bfhi(u2.y) + bfhi(u3.y);
    }
    for (; i < end; ++i){
        int s = csr_src[i];
        uint2 u = *(const uint2*)&h2s[(size_t)s * D_OUT + f * 4];
        a0 += bflo(u.x); a1 += bfhi(u.x);
        a2 += bflo(u.y); a3 += bfhi(u.y);
    }
    uint2 su = *(const uint2*)&h2s[(size_t)d * D_OUT + f * 4];
    a0 += bflo(su.x); a1 += bfhi(su.x);
    a2 += bflo(su.y); a3 += bfhi(su.y);
    const float dd = dinv[d];
    float b0, b1v, b2v, b3v;
    if (isBf16){
        uint2 bu = ((const uint2*)b2raw)[f];
        b0 = bflo(bu.x); b1v = bfhi(bu.x); b2v = bflo(bu.y); b3v = bfhi(bu.y);
    } else {
        float4 bb = ((const float4*)b2raw)[f];
        b0 = bb.x; b1v = bb.y; b2v = bb.z; b3v = bb.w;
    }
    a0 = fmaf(a0, dd, b0); a1 = fmaf(a1, dd, b1v);
    a2 = fmaf(a2, dd, b2v); a3 = fmaf(a3, dd, b3v);
    // log_softmax over 16 values spread across 4 lanes x 4 regs
    float m = fmaxf(fmaxf(a0, a1), fmaxf(a2, a3));
    m = fmaxf(m, __shfl_xor(m, 1, 4));
    m = fmaxf(m, __shfl_xor(m, 2, 4));
    float s = __expf(a0 - m) + __expf(a1 - m) + __expf(a2 - m) + __expf(a3 - m);
    s += __shfl_xor(s, 1, 4);
    s += __shfl_xor(s, 2, 4);
    float ls = m + __logf(s);
    if (isBf16){
        uint2 pk;
        pk.x = f2bu(a0 - ls) | (f2bu(a1 - ls) << 16);
        pk.y = f2bu(a2 - ls) | (f2bu(a3 - ls) << 16);
        *(uint2*)((__hip_bfloat16*)out + (size_t)d * D_OUT + f * 4) = pk;
    } else {
        float4 o4 = make_float4(a0 - ls, a1 - ls, a2 - ls, a3 - ls);
        *(float4*)((float*)out + (size_t)d * D_OUT + f * 4) = o4;
    }
}

extern "C" void kernel_launch(void* const* d_in, const int* in_sizes, int n_in,
                              void* d_out, int out_size, void* d_ws, size_t ws_size,
                              hipStream_t stream)
{
    const unsigned* xraw  = (const unsigned*)d_in[0];
    const int*      ei    = (const int*)d_in[1];
    const unsigned* w1raw = (const unsigned*)d_in[2];
    const unsigned* b1raw = (const unsigned*)d_in[3];
    const unsigned* w2raw = (const unsigned*)d_in[4];
    const unsigned* b2raw = (const unsigned*)d_in[5];

    const int n  = in_sizes[0] / D_IN;   // 100000
    const int ne = in_sizes[1] / 2;      // 1600000
    const int B  = (n + ((1 << WSHIFT) - 1)) >> WSHIFT;   // 98 buckets

    // ws layout (4B words):
    // flags[64] | gcur[128] | dinv[nAl] | off[nAl+64] | csr[neAl] | gbuf[MAXB*BCAP]
    //   | h1s[n*64 bf16] | actb[n*64 bf16] | h2s[n*16 bf16]
    size_t nAl  = ((size_t)n + 255) & ~(size_t)255;
    size_t neAl = ((size_t)ne + 255) & ~(size_t)255;
    int*            flags = (int*)d_ws;
    unsigned*       gcur  = (unsigned*)d_ws + 64;
    float*          dinv  = (float*)(gcur + 128);
    unsigned*       off   = (unsigned*)(dinv + nAl);
    int*            csr   = (int*)(off + nAl + 64);
    unsigned*       gbuf  = (unsigned*)(csr + neAl);
    unsigned short* h1s   = (unsigned short*)(gbuf + (size_t)MAXB * BCAP);
    unsigned short* actb  = h1s + (size_t)n * D_HID;
    unsigned short* h2s   = actb + (size_t)n * D_HID;

    const int nchunk = (ne + CHUNK - 1) / CHUNK;

    k_detect    <<<1, 128, 0, stream>>>(xraw, ei, flags, gcur);
    k_bucketize <<<nchunk, 256, 0, stream>>>(ei, flags, gcur, gbuf, ne, B);
    k_build     <<<B, 1024, 0, stream>>>(gbuf, gcur, off, dinv, csr, n, B);

    k_linear1   <<<256, 256, 0, stream>>>(xraw, w1raw, flags, dinv, h1s, n);
    k_aggA      <<<(n + 15) / 16, 256, 0, stream>>>(off, csr, dinv, h1s, b1raw, flags, actb, n);
    k_linear2   <<<256, 256, 0, stream>>>(actb, w2raw, flags, dinv, h2s, n);
    k_aggB      <<<(n + 63) / 64, 256, 0, stream>>>(off, csr, dinv, h2s, b2raw, flags, d_out, n);
}

// Round 10
// 211.182 us; speedup vs baseline: 1.4758x; 1.0673x over previous
//
#include <hip/hip_runtime.h>
#include <hip/hip_bf16.h>

// GCN 2-layer. Bucketized CSR build (LDS histogram atomics only), pre-scaled bf16
// intermediates (h1s = h1*dinv => per-edge work is pure gather+add), MFMA linears
// (16x16x32 bf16, weights in registers, no LDS).
// flags[0]=1 if floats bf16 else fp32; flags[1]=1 if edge_index int64 else int32.
// Dtypes detected on-device inside k_bucketize (ballot over first 64 words).

constexpr int D_IN  = 128;
constexpr int D_HID = 64;
constexpr int D_OUT = 16;

constexpr int WSHIFT  = 9;       // bucket = dst >> 9 (512 nodes/bucket)
constexpr int MAXB    = 256;     // max buckets (n <= 131072)
constexpr int BCAP    = 12288;   // bucket capacity (mean ~8163 at E/N=16, 1.5x slack)
constexpr int BIN_CAP = 48;      // LDS bin cap per bucket per chunk (mean ~21)
constexpr int CHUNK   = 4096;

typedef __attribute__((ext_vector_type(8))) short bf16x8;
typedef __attribute__((ext_vector_type(4))) float f32x4;

__device__ inline float bflo(unsigned u){ return __uint_as_float(u << 16); }
__device__ inline float bfhi(unsigned u){ return __uint_as_float(u & 0xffff0000u); }
__device__ inline unsigned f2bu(float f){
    __hip_bfloat16 h = __float2bfloat16(f);
    return (unsigned)*reinterpret_cast<unsigned short*>(&h);
}
__device__ inline float sigf(float x){ return 1.0f / (1.0f + __expf(-x)); }

// ---------------- phase 1: bucketize edges by dst>>9 + on-device dtype detect ----------------
__global__ __launch_bounds__(256) void k_bucketize(
    const int* __restrict__ ei, const unsigned* __restrict__ xraw,
    int* __restrict__ flags, unsigned* __restrict__ gcur,
    unsigned* __restrict__ gbuf, int ne, int B)
{
    __shared__ unsigned bcnt[MAXB];
    __shared__ unsigned bbase[MAXB];
    __shared__ unsigned bins[MAXB * BIN_CAP];   // 49 KB
    __shared__ int s_i64;

    const int t = threadIdx.x, lane = t & 63, wv = t >> 6;
    const int e0 = blockIdx.x * CHUNK;

    if (t < MAXB) bcnt[t] = 0u;
    if (wv == 0){
        // int64 detect: odd words ~all zero iff int64 ids
        int w = ei[2 * lane + 1];
        unsigned long long m = __ballot(w == 0);
        if (lane == 0) s_i64 = (__popcll(m) > 48) ? 1 : 0;
        if (blockIdx.x == 0){
            // float dtype detect: bf16 iff word halves are sane bf16 exponents
            unsigned u = xraw[lane];
            unsigned h0 = u & 0xffffu, h1 = u >> 16;
            unsigned ex0 = (h0 >> 7) & 0xffu, ex1 = (h1 >> 7) & 0xffu;
            bool bad0 = !((h0 & 0x7fffu) == 0 || (ex0 >= 97 && ex0 <= 157));
            bool bad1 = !((h1 & 0x7fffu) == 0 || (ex1 >= 97 && ex1 <= 157));
            unsigned long long m0 = __ballot(bad0);
            unsigned long long m1 = __ballot(bad1);
            if (lane == 0){
                int bad = __popcll(m0) + __popcll(m1);
                flags[0] = (bad > 8) ? 0 : 1;
                flags[1] = s_i64;
            }
        }
    }
    __syncthreads();
    const int i64 = s_i64;
    const bool vec = ((ne & 1) == 0);

    #pragma unroll
    for (int k = 0; k < CHUNK / 512; ++k){
        int e = e0 + k * 512 + 2 * t;
        int s0, d0, s1, d1;
        int cntE = 0;
        if (vec && e < ne){                      // paired vector loads (e even, ne even)
            if (i64){
                int4 sp = *(const int4*)&ei[2 * e];
                int4 dp = *(const int4*)&ei[2 * (ne + e)];
                s0 = sp.x; s1 = sp.z; d0 = dp.x; d1 = dp.z;
            } else {
                int2 sp = *(const int2*)&ei[e];
                int2 dp = *(const int2*)&ei[ne + e];
                s0 = sp.x; s1 = sp.y; d0 = dp.x; d1 = dp.y;
            }
            cntE = 2;
        } else {
            if (e < ne){
                if (i64){ s0 = ei[2*e]; d0 = ei[2*(ne+e)]; }
                else    { s0 = ei[e];   d0 = ei[ne+e]; }
                cntE = 1;
                if (e + 1 < ne){
                    if (i64){ s1 = ei[2*(e+1)]; d1 = ei[2*(ne+e+1)]; }
                    else    { s1 = ei[e+1];     d1 = ei[ne+e+1]; }
                    cntE = 2;
                }
            }
        }
        #pragma unroll
        for (int j = 0; j < 2; ++j){
            if (j < cntE){
                int s = j ? s1 : s0, d = j ? d1 : d0;
                int b = d >> WSHIFT;
                unsigned v = ((unsigned)s << WSHIFT) | ((unsigned)d & ((1u << WSHIFT) - 1));
                unsigned p = atomicAdd(&bcnt[b], 1u);
                if (p < (unsigned)BIN_CAP){
                    bins[b * BIN_CAP + p] = v;
                } else {                               // rare overflow: direct
                    unsigned g = atomicAdd(&gcur[b], 1u);
                    gbuf[(size_t)b * BCAP + g] = v;
                }
            }
        }
    }
    __syncthreads();

    if (t < B){
        unsigned c = min(bcnt[t], (unsigned)BIN_CAP);
        bbase[t] = atomicAdd(&gcur[t], c);             // reserve contiguous run
    }
    __syncthreads();

    for (int b = wv; b < B; b += 4){
        unsigned c = min(bcnt[b], (unsigned)BIN_CAP);
        for (unsigned o = lane; o < c; o += 64)
            gbuf[(size_t)b * BCAP + bbase[b] + o] = bins[b * BIN_CAP + o];
    }
}

// ---------------- phase 2: per-bucket hist + scan + csr fill (1024 threads) ----------------
__global__ __launch_bounds__(1024) void k_build(
    const unsigned* __restrict__ gbuf, const unsigned* __restrict__ gcnt,
    unsigned* __restrict__ off, float* __restrict__ dinv, int* __restrict__ csr,
    int n, int B)
{
    __shared__ unsigned hist[512];
    __shared__ unsigned offl[512];
    __shared__ unsigned wsums[8];
    __shared__ unsigned gsc[MAXB];
    __shared__ unsigned bb_s;

    const int t = threadIdx.x, lane = t & 63, wv = t >> 6;
    const int b = blockIdx.x;
    const int base = b << WSHIFT;
    const int nodes = min(512, n - base);

    if (t < B) gsc[t] = gcnt[t];
    if (t < 512) hist[t] = 0u;
    __syncthreads();
    if (t == 0){
        unsigned s = 0;
        for (int i = 0; i < b; ++i) s += gsc[i];
        bb_s = s;
    }
    const unsigned cnt = gsc[b];
    const unsigned* mybuf = gbuf + (size_t)b * BCAP;

    for (unsigned i = t; i < cnt; i += 1024)
        atomicAdd(&hist[mybuf[i] & ((1u << WSHIFT) - 1)], 1u);
    __syncthreads();

    unsigned v = 0, x = 0;
    if (t < 512){
        v = hist[t];
        x = v;
        #pragma unroll
        for (int o = 1; o < 64; o <<= 1){
            unsigned y = __shfl_up(x, o, 64);
            if (lane >= o) x += y;
        }
        if (lane == 63) wsums[wv] = x;
    }
    __syncthreads();
    if (t == 0){
        unsigned run = 0;
        #pragma unroll
        for (int w = 0; w < 8; ++w){ unsigned tv = wsums[w]; wsums[w] = run; run += tv; }
    }
    __syncthreads();
    if (t < 512) offl[t] = x - v + wsums[wv];
    __syncthreads();

    const unsigned bb = bb_s;
    if (t < nodes){
        off[base + t] = bb + offl[t];
        dinv[base + t] = rsqrtf(1.0f + (float)v);
    }
    if (b == B - 1 && t == 0) off[n] = bb + cnt;
    __syncthreads();

    if (t < 512) hist[t] = offl[t];    // cursors <- local offsets
    __syncthreads();

    for (unsigned i = t; i < cnt; i += 1024){
        unsigned rec = mybuf[i];
        unsigned p = atomicAdd(&hist[rec & ((1u << WSHIFT) - 1)], 1u);
        csr[bb + p] = (int)(rec >> WSHIFT);
    }
}

// ---------------- linear 1 (MFMA): h1s(bf16) = (x @ W1) * dinv[node] ----------------
__global__ __launch_bounds__(256) void k_linear1(
    const unsigned* __restrict__ xraw, const unsigned* __restrict__ w1raw,
    const int* __restrict__ flags, const float* __restrict__ dinv,
    unsigned short* __restrict__ h1s, int n)
{
    const int lane = threadIdx.x & 63;
    const int wv   = threadIdx.x >> 6;
    const int m = lane & 15, q = lane >> 4;
    const int isBf16 = flags[0];

    bf16x8 bfr[4][4];
    if (isBf16){
        const unsigned short* w = (const unsigned short*)w1raw;
        #pragma unroll
        for (int kc = 0; kc < 4; ++kc)
            #pragma unroll
            for (int ct = 0; ct < 4; ++ct)
                #pragma unroll
                for (int j = 0; j < 8; ++j)
                    bfr[kc][ct][j] = (short)w[(kc*32 + q*8 + j) * D_HID + ct*16 + m];
    } else {
        const float* w = (const float*)w1raw;
        #pragma unroll
        for (int kc = 0; kc < 4; ++kc)
            #pragma unroll
            for (int ct = 0; ct < 4; ++ct)
                #pragma unroll
                for (int j = 0; j < 8; ++j)
                    bfr[kc][ct][j] = (short)f2bu(w[(kc*32 + q*8 + j) * D_HID + ct*16 + m]);
    }

    const int ntiles = (n + 15) >> 4;
    for (int tile = blockIdx.x * 4 + wv; tile < ntiles; tile += gridDim.x * 4){
        const int node0 = tile << 4;
        int arow = node0 + m; if (arow >= n) arow = n - 1;
        f32x4 ac0 = {0,0,0,0}, ac1 = {0,0,0,0}, ac2 = {0,0,0,0}, ac3 = {0,0,0,0};
        #pragma unroll
        for (int kc = 0; kc < 4; ++kc){
            bf16x8 a;
            if (isBf16){
                uint4 u = *(const uint4*)((const unsigned short*)xraw + (size_t)arow * D_IN + kc*32 + q*8);
                a = *reinterpret_cast<bf16x8*>(&u);
            } else {
                const float* xp = (const float*)xraw + (size_t)arow * D_IN + kc*32 + q*8;
                float4 f0 = *(const float4*)xp;
                float4 f1 = *(const float4*)(xp + 4);
                a[0]=(short)f2bu(f0.x); a[1]=(short)f2bu(f0.y); a[2]=(short)f2bu(f0.z); a[3]=(short)f2bu(f0.w);
                a[4]=(short)f2bu(f1.x); a[5]=(short)f2bu(f1.y); a[6]=(short)f2bu(f1.z); a[7]=(short)f2bu(f1.w);
            }
            ac0 = __builtin_amdgcn_mfma_f32_16x16x32_bf16(a, bfr[kc][0], ac0, 0, 0, 0);
            ac1 = __builtin_amdgcn_mfma_f32_16x16x32_bf16(a, bfr[kc][1], ac1, 0, 0, 0);
            ac2 = __builtin_amdgcn_mfma_f32_16x16x32_bf16(a, bfr[kc][2], ac2, 0, 0, 0);
            ac3 = __builtin_amdgcn_mfma_f32_16x16x32_bf16(a, bfr[kc][3], ac3, 0, 0, 0);
        }
        #pragma unroll
        for (int i = 0; i < 4; ++i){
            int nr = node0 + q*4 + i;
            if (nr < n){
                float di = dinv[nr];
                unsigned short* o = h1s + (size_t)nr * D_HID + m;
                o[0]  = (unsigned short)f2bu(ac0[i] * di);
                o[16] = (unsigned short)f2bu(ac1[i] * di);
                o[32] = (unsigned short)f2bu(ac2[i] * di);
                o[48] = (unsigned short)f2bu(ac3[i] * di);
            }
        }
    }
}

// ---------------- aggA: 4 dst/wave, 16 lanes/dst, uint2 gathers, unroll x4 ----------------
__global__ __launch_bounds__(256) void k_aggA(
    const unsigned* __restrict__ off, const int* __restrict__ csr_src,
    const float* __restrict__ dinv, const unsigned short* __restrict__ h1s,
    const unsigned* __restrict__ b1raw, const int* __restrict__ flags,
    unsigned short* __restrict__ actb, int n)
{
    const int lane = threadIdx.x & 63;
    const int wv   = threadIdx.x >> 6;
    const int grp  = lane >> 4;            // dst within wave (0..3)
    const int f    = lane & 15;            // uint2 index within 64-feature row
    const int d    = (blockIdx.x * 4 + wv) * 4 + grp;
    if (d >= n) return;

    const int beg = (int)off[d], end = (int)off[d + 1];
    float a0=0.f, a1=0.f, a2=0.f, a3=0.f;
    int i = beg;
    for (; i + 4 <= end; i += 4){
        int s0 = csr_src[i], s1 = csr_src[i+1], s2 = csr_src[i+2], s3 = csr_src[i+3];
        uint2 u0 = *(const uint2*)&h1s[(size_t)s0 * D_HID + f * 4];
        uint2 u1 = *(const uint2*)&h1s[(size_t)s1 * D_HID + f * 4];
        uint2 u2 = *(const uint2*)&h1s[(size_t)s2 * D_HID + f * 4];
        uint2 u3 = *(const uint2*)&h1s[(size_t)s3 * D_HID + f * 4];
        a0 += bflo(u0.x) + bflo(u1.x) + bflo(u2.x) + bflo(u3.x);
        a1 += bfhi(u0.x) + bfhi(u1.x) + bfhi(u2.x) + bfhi(u3.x);
        a2 += bflo(u0.y) + bflo(u1.y) + bflo(u2.y) + bflo(u3.y);
        a3 += bfhi(u0.y) + bfhi(u1.y) + bfhi(u2.y) + bfhi(u3.y);
    }
    for (; i < end; ++i){
        int s = csr_src[i];
        uint2 u = *(const uint2*)&h1s[(size_t)s * D_HID + f * 4];
        a0 += bflo(u.x); a1 += bfhi(u.x);
        a2 += bflo(u.y); a3 += bfhi(u.y);
    }
    // self loop + dinv[d] scale + bias + sigmoid
    uint2 su = *(const uint2*)&h1s[(size_t)d * D_HID + f * 4];
    a0 += bflo(su.x); a1 += bfhi(su.x);
    a2 += bflo(su.y); a3 += bfhi(su.y);
    const float dd = dinv[d];
    float b0, b1v, b2v, b3v;
    if (flags[0]){
        uint2 bu = ((const uint2*)b1raw)[f];
        b0 = bflo(bu.x); b1v = bfhi(bu.x); b2v = bflo(bu.y); b3v = bfhi(bu.y);
    } else {
        float4 bb = ((const float4*)b1raw)[f];
        b0 = bb.x; b1v = bb.y; b2v = bb.z; b3v = bb.w;
    }
    uint2 pk;
    pk.x = f2bu(sigf(fmaf(a0, dd, b0))) | (f2bu(sigf(fmaf(a1, dd, b1v))) << 16);
    pk.y = f2bu(sigf(fmaf(a2, dd, b2v))) | (f2bu(sigf(fmaf(a3, dd, b3v))) << 16);
    *(uint2*)&actb[(size_t)d * D_HID + f * 4] = pk;
}

// ---------------- linear 2 (MFMA): h2s(bf16) = (act @ W2) * dinv[node] ----------------
__global__ __launch_bounds__(256) void k_linear2(
    const unsigned short* __restrict__ actb, const unsigned* __restrict__ w2raw,
    const int* __restrict__ flags, const float* __restrict__ dinv,
    unsigned short* __restrict__ h2s, int n)
{
    const int lane = threadIdx.x & 63;
    const int wv   = threadIdx.x >> 6;
    const int m = lane & 15, q = lane >> 4;
    const int isBf16 = flags[0];

    bf16x8 bfr[2];
    if (isBf16){
        const unsigned short* w = (const unsigned short*)w2raw;
        #pragma unroll
        for (int kc = 0; kc < 2; ++kc)
            #pragma unroll
            for (int j = 0; j < 8; ++j)
                bfr[kc][j] = (short)w[(kc*32 + q*8 + j) * D_OUT + m];
    } else {
        const float* w = (const float*)w2raw;
        #pragma unroll
        for (int kc = 0; kc < 2; ++kc)
            #pragma unroll
            for (int j = 0; j < 8; ++j)
                bfr[kc][j] = (short)f2bu(w[(kc*32 + q*8 + j) * D_OUT + m]);
    }

    const int ntiles = (n + 15) >> 4;
    for (int tile = blockIdx.x * 4 + wv; tile < ntiles; tile += gridDim.x * 4){
        const int node0 = tile << 4;
        int arow = node0 + m; if (arow >= n) arow = n - 1;
        f32x4 acc = {0,0,0,0};
        #pragma unroll
        for (int kc = 0; kc < 2; ++kc){
            uint4 u = *(const uint4*)(actb + (size_t)arow * D_HID + kc*32 + q*8);
            bf16x8 a = *reinterpret_cast<bf16x8*>(&u);
            acc = __builtin_amdgcn_mfma_f32_16x16x32_bf16(a, bfr[kc], acc, 0, 0, 0);
        }
        #pragma unroll
        for (int i = 0; i < 4; ++i){
            int nr = node0 + q*4 + i;
            if (nr < n)
                h2s[(size_t)nr * D_OUT + m] = (unsigned short)f2bu(acc[i] * dinv[nr]);
        }
    }
}

// ---------------- aggB: 16 dst/wave, 4 lanes/dst, uint2 gathers, unroll x4 ----------------
__global__ __launch_bounds__(256) void k_aggB(
    const unsigned* __restrict__ off, const int* __restrict__ csr_src,
    const float* __restrict__ dinv, const unsigned short* __restrict__ h2s,
    const unsigned* __restrict__ b2raw, const int* __restrict__ flags,
    void* __restrict__ out, int n)
{
    const int lane = threadIdx.x & 63;
    const int wv   = threadIdx.x >> 6;
    const int grp  = lane >> 2;            // dst within wave (0..15)
    const int f    = lane & 3;             // uint2 index within 16-feature row
    const int d    = (blockIdx.x * 4 + wv) * 16 + grp;
    const int isBf16 = flags[0];
    if (d >= n) return;

    const int beg = (int)off[d], end = (int)off[d + 1];
    float a0=0.f, a1=0.f, a2=0.f, a3=0.f;
    int i = beg;
    for (; i + 4 <= end; i += 4){
        int s0 = csr_src[i], s1 = csr_src[i+1], s2 = csr_src[i+2], s3 = csr_src[i+3];
        uint2 u0 = *(const uint2*)&h2s[(size_t)s0 * D_OUT + f * 4];
        uint2 u1 = *(const uint2*)&h2s[(size_t)s1 * D_OUT + f * 4];
        uint2 u2 = *(const uint2*)&h2s[(size_t)s2 * D_OUT + f * 4];
        uint2 u3 = *(const uint2*)&h2s[(size_t)s3 * D_OUT + f * 4];
        a0 += bflo(u0.x) + bflo(u1.x) + bflo(u2.x) + bflo(u3.x);
        a1 += bfhi(u0.x) + bfhi(u1.x) + bfhi(u2.x) + bfhi(u3.x);
        a2 += bflo(u0.y) + bflo(u1.y) + bflo(u2.y) + bflo(u3.y);
        a3 += bfhi(u0.y) + bfhi(u1.y) + bfhi(u2.y) + bfhi(u3.y);
    }
    for (; i < end; ++i){
        int s = csr_src[i];
        uint2 u = *(const uint2*)&h2s[(size_t)s * D_OUT + f * 4];
        a0 += bflo(u.x); a1 += bfhi(u.x);
        a2 += bflo(u.y); a3 += bfhi(u.y);
    }
    uint2 su = *(const uint2*)&h2s[(size_t)d * D_OUT + f * 4];
    a0 += bflo(su.x); a1 += bfhi(su.x);
    a2 += bflo(su.y); a3 += bfhi(su.y);
    const float dd = dinv[d];
    float b0, b1v, b2v, b3v;
    if (isBf16){
        uint2 bu = ((const uint2*)b2raw)[f];
        b0 = bflo(bu.x); b1v = bfhi(bu.x); b2v = bflo(bu.y); b3v = bfhi(bu.y);
    } else {
        float4 bb = ((const float4*)b2raw)[f];
        b0 = bb.x; b1v = bb.y; b2v = bb.z; b3v = bb.w;
    }
    a0 = fmaf(a0, dd, b0); a1 = fmaf(a1, dd, b1v);
    a2 = fmaf(a2, dd, b2v); a3 = fmaf(a3, dd, b3v);
    // log_softmax over 16 values spread across 4 lanes x 4 regs
    float m = fmaxf(fmaxf(a0, a1), fmaxf(a2, a3));
    m = fmaxf(m, __shfl_xor(m, 1, 4));
    m = fmaxf(m, __shfl_xor(m, 2, 4));
    float s = __expf(a0 - m) + __expf(a1 - m) + __expf(a2 - m) + __expf(a3 - m);
    s += __shfl_xor(s, 1, 4);
    s += __shfl_xor(s, 2, 4);
    float ls = m + __logf(s);
    if (isBf16){
        uint2 pk;
        pk.x = f2bu(a0 - ls) | (f2bu(a1 - ls) << 16);
        pk.y = f2bu(a2 - ls) | (f2bu(a3 - ls) << 16);
        *(uint2*)((__hip_bfloat16*)out + (size_t)d * D_OUT + f * 4) = pk;
    } else {
        float4 o4 = make_float4(a0 - ls, a1 - ls, a2 - ls, a3 - ls);
        *(float4*)((float*)out + (size_t)d * D_OUT + f * 4) = o4;
    }
}

extern "C" void kernel_launch(void* const* d_in, const int* in_sizes, int n_in,
                              void* d_out, int out_size, void* d_ws, size_t ws_size,
                              hipStream_t stream)
{
    const unsigned* xraw  = (const unsigned*)d_in[0];
    const int*      ei    = (const int*)d_in[1];
    const unsigned* w1raw = (const unsigned*)d_in[2];
    const unsigned* b1raw = (const unsigned*)d_in[3];
    const unsigned* w2raw = (const unsigned*)d_in[4];
    const unsigned* b2raw = (const unsigned*)d_in[5];

    const int n  = in_sizes[0] / D_IN;   // 100000
    const int ne = in_sizes[1] / 2;      // 1600000
    const int B  = (n + ((1 << WSHIFT) - 1)) >> WSHIFT;   // 196 buckets

    // ws layout (4B words):
    // flags[64] | gcur[256] | dinv[nAl] | off[nAl+64] | csr[neAl] | gbuf[MAXB*BCAP]
    //   | h1s[n*64 bf16] | actb[n*64 bf16] | h2s[n*16 bf16]
    size_t nAl  = ((size_t)n + 255) & ~(size_t)255;
    size_t neAl = ((size_t)ne + 255) & ~(size_t)255;
    int*            flags = (int*)d_ws;
    unsigned*       gcur  = (unsigned*)d_ws + 64;
    float*          dinv  = (float*)(gcur + 256);
    unsigned*       off   = (unsigned*)(dinv + nAl);
    int*            csr   = (int*)(off + nAl + 64);
    unsigned*       gbuf  = (unsigned*)(csr + neAl);
    unsigned short* h1s   = (unsigned short*)(gbuf + (size_t)MAXB * BCAP);
    unsigned short* actb  = h1s + (size_t)n * D_HID;
    unsigned short* h2s   = actb + (size_t)n * D_HID;

    const int nchunk = (ne + CHUNK - 1) / CHUNK;

    hipMemsetAsync(gcur, 0, MAXB * sizeof(unsigned), stream);
    k_bucketize <<<nchunk, 256, 0, stream>>>(ei, xraw, flags, gcur, gbuf, ne, B);
    k_build     <<<B, 1024, 0, stream>>>(gbuf, gcur, off, dinv, csr, n, B);

    k_linear1   <<<256, 256, 0, stream>>>(xraw, w1raw, flags, dinv, h1s, n);
    k_aggA      <<<(n + 15) / 16, 256, 0, stream>>>(off, csr, dinv, h1s, b1raw, flags, actb, n);
    k_linear2   <<<256, 256, 0, stream>>>(actb, w2raw, flags, dinv, h2s, n);
    k_aggB      <<<(n + 63) / 64, 256, 0, stream>>>(off, csr, dinv, h2s, b2raw, flags, d_out, n);
}

// Round 11
// 211.074 us; speedup vs baseline: 1.4766x; 1.0005x over previous
//
#include <hip/hip_runtime.h>
#include <hip/hip_bf16.h>

// GCN 2-layer. Bucketized CSR build with PADDED runs (each dst's edge list padded
// to a multiple of 8 with sentinel index n -> all-zero feature row): aggregation
// loops are tail-free, csr loads are aligned uint4, 8 gathers in flight.
// Pre-scaled bf16 intermediates (h1s = h1*dinv => per-edge work = gather+add).
// MFMA linears (16x16x32 bf16, weights in registers, no LDS).
// flags[0]=1 if floats bf16 else fp32; flags[1]=1 if edge_index int64 else int32.

constexpr int D_IN  = 128;
constexpr int D_HID = 64;
constexpr int D_OUT = 16;

constexpr int WSHIFT  = 9;       // bucket = dst >> 9 (512 nodes/bucket)
constexpr int MAXB    = 256;     // max buckets (n <= 131072)
constexpr int BCAP    = 12288;   // gbuf bucket capacity (mean ~8163 at E/N=16)
constexpr int CSRCAP  = 16384;   // csr bucket region (BCAP + 512*8 padding, 8-aligned)
constexpr int BIN_CAP = 48;      // LDS bin cap per bucket per chunk (mean ~21)
constexpr int CHUNK   = 4096;

typedef __attribute__((ext_vector_type(8))) short bf16x8;
typedef __attribute__((ext_vector_type(4))) float f32x4;

__device__ inline float bflo(unsigned u){ return __uint_as_float(u << 16); }
__device__ inline float bfhi(unsigned u){ return __uint_as_float(u & 0xffff0000u); }
__device__ inline unsigned f2bu(float f){
    __hip_bfloat16 h = __float2bfloat16(f);
    return (unsigned)*reinterpret_cast<unsigned short*>(&h);
}
__device__ inline float sigf(float x){ return 1.0f / (1.0f + __expf(-x)); }

// ---------------- phase 1: bucketize edges by dst>>9 + on-device dtype detect ----------------
__global__ __launch_bounds__(256) void k_bucketize(
    const int* __restrict__ ei, const unsigned* __restrict__ xraw,
    int* __restrict__ flags, unsigned* __restrict__ gcur,
    unsigned* __restrict__ gbuf, int ne, int B)
{
    __shared__ unsigned bcnt[MAXB];
    __shared__ unsigned bbase[MAXB];
    __shared__ unsigned bins[MAXB * BIN_CAP];   // 49 KB
    __shared__ int s_i64;

    const int t = threadIdx.x, lane = t & 63, wv = t >> 6;
    const int e0 = blockIdx.x * CHUNK;

    if (t < MAXB) bcnt[t] = 0u;
    if (wv == 0){
        int w = ei[2 * lane + 1];
        unsigned long long m = __ballot(w == 0);
        if (lane == 0) s_i64 = (__popcll(m) > 48) ? 1 : 0;
        if (blockIdx.x == 0){
            unsigned u = xraw[lane];
            unsigned h0 = u & 0xffffu, h1 = u >> 16;
            unsigned ex0 = (h0 >> 7) & 0xffu, ex1 = (h1 >> 7) & 0xffu;
            bool bad0 = !((h0 & 0x7fffu) == 0 || (ex0 >= 97 && ex0 <= 157));
            bool bad1 = !((h1 & 0x7fffu) == 0 || (ex1 >= 97 && ex1 <= 157));
            unsigned long long m0 = __ballot(bad0);
            unsigned long long m1 = __ballot(bad1);
            if (lane == 0){
                int bad = __popcll(m0) + __popcll(m1);
                flags[0] = (bad > 8) ? 0 : 1;
                flags[1] = s_i64;
            }
        }
    }
    __syncthreads();
    const int i64 = s_i64;
    const bool vec = ((ne & 1) == 0);

    #pragma unroll
    for (int k = 0; k < CHUNK / 512; ++k){
        int e = e0 + k * 512 + 2 * t;
        int s0, d0, s1, d1;
        int cntE = 0;
        if (vec && e < ne){
            if (i64){
                int4 sp = *(const int4*)&ei[2 * e];
                int4 dp = *(const int4*)&ei[2 * (ne + e)];
                s0 = sp.x; s1 = sp.z; d0 = dp.x; d1 = dp.z;
            } else {
                int2 sp = *(const int2*)&ei[e];
                int2 dp = *(const int2*)&ei[ne + e];
                s0 = sp.x; s1 = sp.y; d0 = dp.x; d1 = dp.y;
            }
            cntE = 2;
        } else {
            if (e < ne){
                if (i64){ s0 = ei[2*e]; d0 = ei[2*(ne+e)]; }
                else    { s0 = ei[e];   d0 = ei[ne+e]; }
                cntE = 1;
                if (e + 1 < ne){
                    if (i64){ s1 = ei[2*(e+1)]; d1 = ei[2*(ne+e+1)]; }
                    else    { s1 = ei[e+1];     d1 = ei[ne+e+1]; }
                    cntE = 2;
                }
            }
        }
        #pragma unroll
        for (int j = 0; j < 2; ++j){
            if (j < cntE){
                int s = j ? s1 : s0, d = j ? d1 : d0;
                int b = d >> WSHIFT;
                unsigned v = ((unsigned)s << WSHIFT) | ((unsigned)d & ((1u << WSHIFT) - 1));
                unsigned p = atomicAdd(&bcnt[b], 1u);
                if (p < (unsigned)BIN_CAP){
                    bins[b * BIN_CAP + p] = v;
                } else {
                    unsigned g = atomicAdd(&gcur[b], 1u);
                    gbuf[(size_t)b * BCAP + g] = v;
                }
            }
        }
    }
    __syncthreads();

    if (t < B){
        unsigned c = min(bcnt[t], (unsigned)BIN_CAP);
        bbase[t] = atomicAdd(&gcur[t], c);
    }
    __syncthreads();

    for (int b = wv; b < B; b += 4){
        unsigned c = min(bcnt[b], (unsigned)BIN_CAP);
        for (unsigned o = lane; o < c; o += 64)
            gbuf[(size_t)b * BCAP + bbase[b] + o] = bins[b * BIN_CAP + o];
    }
}

// ---------------- phase 2: per-bucket hist + scan + PADDED csr fill ----------------
// Fixed region per bucket (bb = b*CSRCAP): no cross-bucket prefix needed.
__global__ __launch_bounds__(1024) void k_build(
    const unsigned* __restrict__ gbuf, const unsigned* __restrict__ gcnt,
    unsigned* __restrict__ off, unsigned* __restrict__ offend,
    float* __restrict__ dinv, int* __restrict__ csr, int n, int B)
{
    __shared__ unsigned hist[512];
    __shared__ unsigned offl[512];
    __shared__ unsigned wsums[8];

    const int t = threadIdx.x, lane = t & 63, wv = t >> 6;
    const int b = blockIdx.x;
    const int base = b << WSHIFT;
    const int nodes = min(512, n - base);
    const unsigned bb = (unsigned)b * CSRCAP;

    if (t < 512) hist[t] = 0u;
    __syncthreads();
    const unsigned cnt = gcnt[b];
    const unsigned* mybuf = gbuf + (size_t)b * BCAP;

    for (unsigned i = t; i < cnt; i += 1024)
        atomicAdd(&hist[mybuf[i] & ((1u << WSHIFT) - 1)], 1u);
    __syncthreads();

    unsigned v = 0, p = 0, x = 0;
    if (t < 512){
        v = hist[t];                                   // real in-degree
        p = (v + 7u) & ~7u;                            // padded run length
        x = p;
        #pragma unroll
        for (int o = 1; o < 64; o <<= 1){
            unsigned y = __shfl_up(x, o, 64);
            if (lane >= o) x += y;
        }
        if (lane == 63) wsums[wv] = x;
    }
    __syncthreads();
    if (t == 0){
        unsigned run = 0;
        #pragma unroll
        for (int w = 0; w < 8; ++w){ unsigned tv = wsums[w]; wsums[w] = run; run += tv; }
    }
    __syncthreads();
    if (t < 512) offl[t] = x - p + wsums[wv];          // exclusive scan of padded lens
    __syncthreads();

    if (t < nodes){
        off[base + t]    = bb + offl[t];
        offend[base + t] = bb + offl[t] + p;
        dinv[base + t]   = rsqrtf(1.0f + (float)v);
    }
    __syncthreads();

    if (t < 512) hist[t] = offl[t];                    // cursors <- local offsets
    __syncthreads();

    for (unsigned i = t; i < cnt; i += 1024){
        unsigned rec = mybuf[i];
        unsigned pos = atomicAdd(&hist[rec & ((1u << WSHIFT) - 1)], 1u);
        csr[bb + pos] = (int)(rec >> WSHIFT);
    }
    __syncthreads();

    if (t < nodes){                                    // pad with sentinel n (zero row)
        unsigned s = offl[t] + v, e2 = offl[t] + p;
        for (unsigned j = s; j < e2; ++j) csr[bb + j] = n;
    }
}

// ---------------- linear 1 (MFMA): h1s(bf16) = (x @ W1) * dinv[node]; row n = 0 ----------------
__global__ __launch_bounds__(256) void k_linear1(
    const unsigned* __restrict__ xraw, const unsigned* __restrict__ w1raw,
    const int* __restrict__ flags, const float* __restrict__ dinv,
    unsigned short* __restrict__ h1s, int n)
{
    const int lane = threadIdx.x & 63;
    const int wv   = threadIdx.x >> 6;
    const int m = lane & 15, q = lane >> 4;
    const int isBf16 = flags[0];

    if (blockIdx.x == 0 && threadIdx.x < 16)           // sentinel zero row
        ((uint2*)(h1s + (size_t)n * D_HID))[threadIdx.x] = make_uint2(0u, 0u);

    bf16x8 bfr[4][4];
    if (isBf16){
        const unsigned short* w = (const unsigned short*)w1raw;
        #pragma unroll
        for (int kc = 0; kc < 4; ++kc)
            #pragma unroll
            for (int ct = 0; ct < 4; ++ct)
                #pragma unroll
                for (int j = 0; j < 8; ++j)
                    bfr[kc][ct][j] = (short)w[(kc*32 + q*8 + j) * D_HID + ct*16 + m];
    } else {
        const float* w = (const float*)w1raw;
        #pragma unroll
        for (int kc = 0; kc < 4; ++kc)
            #pragma unroll
            for (int ct = 0; ct < 4; ++ct)
                #pragma unroll
                for (int j = 0; j < 8; ++j)
                    bfr[kc][ct][j] = (short)f2bu(w[(kc*32 + q*8 + j) * D_HID + ct*16 + m]);
    }

    const int ntiles = (n + 15) >> 4;
    for (int tile = blockIdx.x * 4 + wv; tile < ntiles; tile += gridDim.x * 4){
        const int node0 = tile << 4;
        int arow = node0 + m; if (arow >= n) arow = n - 1;
        f32x4 ac0 = {0,0,0,0}, ac1 = {0,0,0,0}, ac2 = {0,0,0,0}, ac3 = {0,0,0,0};
        #pragma unroll
        for (int kc = 0; kc < 4; ++kc){
            bf16x8 a;
            if (isBf16){
                uint4 u = *(const uint4*)((const unsigned short*)xraw + (size_t)arow * D_IN + kc*32 + q*8);
                a = *reinterpret_cast<bf16x8*>(&u);
            } else {
                const float* xp = (const float*)xraw + (size_t)arow * D_IN + kc*32 + q*8;
                float4 f0 = *(const float4*)xp;
                float4 f1 = *(const float4*)(xp + 4);
                a[0]=(short)f2bu(f0.x); a[1]=(short)f2bu(f0.y); a[2]=(short)f2bu(f0.z); a[3]=(short)f2bu(f0.w);
                a[4]=(short)f2bu(f1.x); a[5]=(short)f2bu(f1.y); a[6]=(short)f2bu(f1.z); a[7]=(short)f2bu(f1.w);
            }
            ac0 = __builtin_amdgcn_mfma_f32_16x16x32_bf16(a, bfr[kc][0], ac0, 0, 0, 0);
            ac1 = __builtin_amdgcn_mfma_f32_16x16x32_bf16(a, bfr[kc][1], ac1, 0, 0, 0);
            ac2 = __builtin_amdgcn_mfma_f32_16x16x32_bf16(a, bfr[kc][2], ac2, 0, 0, 0);
            ac3 = __builtin_amdgcn_mfma_f32_16x16x32_bf16(a, bfr[kc][3], ac3, 0, 0, 0);
        }
        #pragma unroll
        for (int i = 0; i < 4; ++i){
            int nr = node0 + q*4 + i;
            if (nr < n){
                float di = dinv[nr];
                unsigned short* o = h1s + (size_t)nr * D_HID + m;
                o[0]  = (unsigned short)f2bu(ac0[i] * di);
                o[16] = (unsigned short)f2bu(ac1[i] * di);
                o[32] = (unsigned short)f2bu(ac2[i] * di);
                o[48] = (unsigned short)f2bu(ac3[i] * di);
            }
        }
    }
}

// ---------------- aggA: 4 dst/wave, 16 lanes/dst, tail-free unroll x8 ----------------
__global__ __launch_bounds__(256) void k_aggA(
    const unsigned* __restrict__ off, const unsigned* __restrict__ offend,
    const int* __restrict__ csr_src,
    const float* __restrict__ dinv, const unsigned short* __restrict__ h1s,
    const unsigned* __restrict__ b1raw, const int* __restrict__ flags,
    unsigned short* __restrict__ actb, int n)
{
    const int lane = threadIdx.x & 63;
    const int wv   = threadIdx.x >> 6;
    const int grp  = lane >> 4;            // dst within wave (0..3)
    const int f    = lane & 15;            // uint2 index within 64-feature row
    const int d    = (blockIdx.x * 4 + wv) * 4 + grp;
    if (d >= n) return;

    const int beg = (int)off[d], end = (int)offend[d];   // multiple of 8, 8-aligned
    float a0=0.f, a1=0.f, a2=0.f, a3=0.f;
    for (int i = beg; i < end; i += 8){
        uint4 cA = *(const uint4*)&csr_src[i];
        uint4 cB = *(const uint4*)&csr_src[i + 4];
        uint2 u0 = *(const uint2*)&h1s[(size_t)(unsigned)cA.x * D_HID + f * 4];
        uint2 u1 = *(const uint2*)&h1s[(size_t)(unsigned)cA.y * D_HID + f * 4];
        uint2 u2 = *(const uint2*)&h1s[(size_t)(unsigned)cA.z * D_HID + f * 4];
        uint2 u3 = *(const uint2*)&h1s[(size_t)(unsigned)cA.w * D_HID + f * 4];
        uint2 u4 = *(const uint2*)&h1s[(size_t)(unsigned)cB.x * D_HID + f * 4];
        uint2 u5 = *(const uint2*)&h1s[(size_t)(unsigned)cB.y * D_HID + f * 4];
        uint2 u6 = *(const uint2*)&h1s[(size_t)(unsigned)cB.z * D_HID + f * 4];
        uint2 u7 = *(const uint2*)&h1s[(size_t)(unsigned)cB.w * D_HID + f * 4];
        a0 += bflo(u0.x) + bflo(u1.x) + bflo(u2.x) + bflo(u3.x)
            + bflo(u4.x) + bflo(u5.x) + bflo(u6.x) + bflo(u7.x);
        a1 += bfhi(u0.x) + bfhi(u1.x) + bfhi(u2.x) + bfhi(u3.x)
            + bfhi(u4.x) + bfhi(u5.x) + bfhi(u6.x) + bfhi(u7.x);
        a2 += bflo(u0.y) + bflo(u1.y) + bflo(u2.y) + bflo(u3.y)
            + bflo(u4.y) + bflo(u5.y) + bflo(u6.y) + bflo(u7.y);
        a3 += bfhi(u0.y) + bfhi(u1.y) + bfhi(u2.y) + bfhi(u3.y)
            + bfhi(u4.y) + bfhi(u5.y) + bfhi(u6.y) + bfhi(u7.y);
    }
    // self loop + dinv[d] scale + bias + sigmoid
    uint2 su = *(const uint2*)&h1s[(size_t)d * D_HID + f * 4];
    a0 += bflo(su.x); a1 += bfhi(su.x);
    a2 += bflo(su.y); a3 += bfhi(su.y);
    const float dd = dinv[d];
    float b0, b1v, b2v, b3v;
    if (flags[0]){
        uint2 bu = ((const uint2*)b1raw)[f];
        b0 = bflo(bu.x); b1v = bfhi(bu.x); b2v = bflo(bu.y); b3v = bfhi(bu.y);
    } else {
        float4 bb = ((const float4*)b1raw)[f];
        b0 = bb.x; b1v = bb.y; b2v = bb.z; b3v = bb.w;
    }
    uint2 pk;
    pk.x = f2bu(sigf(fmaf(a0, dd, b0))) | (f2bu(sigf(fmaf(a1, dd, b1v))) << 16);
    pk.y = f2bu(sigf(fmaf(a2, dd, b2v))) | (f2bu(sigf(fmaf(a3, dd, b3v))) << 16);
    *(uint2*)&actb[(size_t)d * D_HID + f * 4] = pk;
}

// ---------------- linear 2 (MFMA): h2s(bf16) = (act @ W2) * dinv[node]; row n = 0 ----------------
__global__ __launch_bounds__(256) void k_linear2(
    const unsigned short* __restrict__ actb, const unsigned* __restrict__ w2raw,
    const int* __restrict__ flags, const float* __restrict__ dinv,
    unsigned short* __restrict__ h2s, int n)
{
    const int lane = threadIdx.x & 63;
    const int wv   = threadIdx.x >> 6;
    const int m = lane & 15, q = lane >> 4;
    const int isBf16 = flags[0];

    if (blockIdx.x == 0 && threadIdx.x < 4)            // sentinel zero row
        ((uint2*)(h2s + (size_t)n * D_OUT))[threadIdx.x] = make_uint2(0u, 0u);

    bf16x8 bfr[2];
    if (isBf16){
        const unsigned short* w = (const unsigned short*)w2raw;
        #pragma unroll
        for (int kc = 0; kc < 2; ++kc)
            #pragma unroll
            for (int j = 0; j < 8; ++j)
                bfr[kc][j] = (short)w[(kc*32 + q*8 + j) * D_OUT + m];
    } else {
        const float* w = (const float*)w2raw;
        #pragma unroll
        for (int kc = 0; kc < 2; ++kc)
            #pragma unroll
            for (int j = 0; j < 8; ++j)
                bfr[kc][j] = (short)f2bu(w[(kc*32 + q*8 + j) * D_OUT + m]);
    }

    const int ntiles = (n + 15) >> 4;
    for (int tile = blockIdx.x * 4 + wv; tile < ntiles; tile += gridDim.x * 4){
        const int node0 = tile << 4;
        int arow = node0 + m; if (arow >= n) arow = n - 1;
        f32x4 acc = {0,0,0,0};
        #pragma unroll
        for (int kc = 0; kc < 2; ++kc){
            uint4 u = *(const uint4*)(actb + (size_t)arow * D_HID + kc*32 + q*8);
            bf16x8 a = *reinterpret_cast<bf16x8*>(&u);
            acc = __builtin_amdgcn_mfma_f32_16x16x32_bf16(a, bfr[kc], acc, 0, 0, 0);
        }
        #pragma unroll
        for (int i = 0; i < 4; ++i){
            int nr = node0 + q*4 + i;
            if (nr < n)
                h2s[(size_t)nr * D_OUT + m] = (unsigned short)f2bu(acc[i] * dinv[nr]);
        }
    }
}

// ---------------- aggB: 16 dst/wave, 4 lanes/dst, tail-free unroll x8 ----------------
__global__ __launch_bounds__(256) void k_aggB(
    const unsigned* __restrict__ off, const unsigned* __restrict__ offend,
    const int* __restrict__ csr_src,
    const float* __restrict__ dinv, const unsigned short* __restrict__ h2s,
    const unsigned* __restrict__ b2raw, const int* __restrict__ flags,
    void* __restrict__ out, int n)
{
    const int lane = threadIdx.x & 63;
    const int wv   = threadIdx.x >> 6;
    const int grp  = lane >> 2;            // dst within wave (0..15)
    const int f    = lane & 3;             // uint2 index within 16-feature row
    const int d    = (blockIdx.x * 4 + wv) * 16 + grp;
    const int isBf16 = flags[0];
    if (d >= n) return;

    const int beg = (int)off[d], end = (int)offend[d];
    float a0=0.f, a1=0.f, a2=0.f, a3=0.f;
    for (int i = beg; i < end; i += 8){
        uint4 cA = *(const uint4*)&csr_src[i];
        uint4 cB = *(const uint4*)&csr_src[i + 4];
        uint2 u0 = *(const uint2*)&h2s[(size_t)(unsigned)cA.x * D_OUT + f * 4];
        uint2 u1 = *(const uint2*)&h2s[(size_t)(unsigned)cA.y * D_OUT + f * 4];
        uint2 u2 = *(const uint2*)&h2s[(size_t)(unsigned)cA.z * D_OUT + f * 4];
        uint2 u3 = *(const uint2*)&h2s[(size_t)(unsigned)cA.w * D_OUT + f * 4];
        uint2 u4 = *(const uint2*)&h2s[(size_t)(unsigned)cB.x * D_OUT + f * 4];
        uint2 u5 = *(const uint2*)&h2s[(size_t)(unsigned)cB.y * D_OUT + f * 4];
        uint2 u6 = *(const uint2*)&h2s[(size_t)(unsigned)cB.z * D_OUT + f * 4];
        uint2 u7 = *(const uint2*)&h2s[(size_t)(unsigned)cB.w * D_OUT + f * 4];
        a0 += bflo(u0.x) + bflo(u1.x) + bflo(u2.x) + bflo(u3.x)
            + bflo(u4.x) + bflo(u5.x) + bflo(u6.x) + bflo(u7.x);
        a1 += bfhi(u0.x) + bfhi(u1.x) + bfhi(u2.x) + bfhi(u3.x)
            + bfhi(u4.x) + bfhi(u5.x) + bfhi(u6.x) + bfhi(u7.x);
        a2 += bflo(u0.y) + bflo(u1.y) + bflo(u2.y) + bflo(u3.y)
            + bflo(u4.y) + bflo(u5.y) + bflo(u6.y) + bflo(u7.y);
        a3 += bfhi(u0.y) + bfhi(u1.y) + bfhi(u2.y) + bfhi(u3.y)
            + bfhi(u4.y) + bfhi(u5.y) + bfhi(u6.y) + bfhi(u7.y);
    }
    uint2 su = *(const uint2*)&h2s[(size_t)d * D_OUT + f * 4];
    a0 += bflo(su.x); a1 += bfhi(su.x);
    a2 += bflo(su.y); a3 += bfhi(su.y);
    const float dd = dinv[d];
    float b0, b1v, b2v, b3v;
    if (isBf16){
        uint2 bu = ((const uint2*)b2raw)[f];
        b0 = bflo(bu.x); b1v = bfhi(bu.x); b2v = bflo(bu.y); b3v = bfhi(bu.y);
    } else {
        float4 bb = ((const float4*)b2raw)[f];
        b0 = bb.x; b1v = bb.y; b2v = bb.z; b3v = bb.w;
    }
    a0 = fmaf(a0, dd, b0); a1 = fmaf(a1, dd, b1v);
    a2 = fmaf(a2, dd, b2v); a3 = fmaf(a3, dd, b3v);
    float m = fmaxf(fmaxf(a0, a1), fmaxf(a2, a3));
    m = fmaxf(m, __shfl_xor(m, 1, 4));
    m = fmaxf(m, __shfl_xor(m, 2, 4));
    float s = __expf(a0 - m) + __expf(a1 - m) + __expf(a2 - m) + __expf(a3 - m);
    s += __shfl_xor(s, 1, 4);
    s += __shfl_xor(s, 2, 4);
    float ls = m + __logf(s);
    if (isBf16){
        uint2 pk;
        pk.x = f2bu(a0 - ls) | (f2bu(a1 - ls) << 16);
        pk.y = f2bu(a2 - ls) | (f2bu(a3 - ls) << 16);
        *(uint2*)((__hip_bfloat16*)out + (size_t)d * D_OUT + f * 4) = pk;
    } else {
        float4 o4 = make_float4(a0 - ls, a1 - ls, a2 - ls, a3 - ls);
        *(float4*)((float*)out + (size_t)d * D_OUT + f * 4) = o4;
    }
}

extern "C" void kernel_launch(void* const* d_in, const int* in_sizes, int n_in,
                              void* d_out, int out_size, void* d_ws, size_t ws_size,
                              hipStream_t stream)
{
    const unsigned* xraw  = (const unsigned*)d_in[0];
    const int*      ei    = (const int*)d_in[1];
    const unsigned* w1raw = (const unsigned*)d_in[2];
    const unsigned* b1raw = (const unsigned*)d_in[3];
    const unsigned* w2raw = (const unsigned*)d_in[4];
    const unsigned* b2raw = (const unsigned*)d_in[5];

    const int n  = in_sizes[0] / D_IN;   // 100000
    const int ne = in_sizes[1] / 2;      // 1600000
    const int B  = (n + ((1 << WSHIFT) - 1)) >> WSHIFT;   // 196 buckets

    // ws layout (4B words):
    // flags[64] | gcur[256] | dinv[nAl] | off[nAl] | offend[nAl] | csr[MAXB*CSRCAP]
    //   | gbuf[MAXB*BCAP] | h1s[(n+1)*64 bf16] | actb[n*64 bf16] | h2s[(n+1)*16 bf16]
    size_t nAl = ((size_t)n + 255) & ~(size_t)255;
    int*            flags  = (int*)d_ws;
    unsigned*       gcur   = (unsigned*)d_ws + 64;
    float*          dinv   = (float*)(gcur + 256);
    unsigned*       off    = (unsigned*)(dinv + nAl);
    unsigned*       offend = off + nAl;
    int*            csr    = (int*)(offend + nAl);
    unsigned*       gbuf   = (unsigned*)(csr + (size_t)MAXB * CSRCAP);
    unsigned short* h1s    = (unsigned short*)(gbuf + (size_t)MAXB * BCAP);
    unsigned short* actb   = h1s + (size_t)(n + 16) * D_HID;
    unsigned short* h2s    = actb + (size_t)n * D_HID;

    const int nchunk = (ne + CHUNK - 1) / CHUNK;

    hipMemsetAsync(gcur, 0, MAXB * sizeof(unsigned), stream);
    k_bucketize <<<nchunk, 256, 0, stream>>>(ei, xraw, flags, gcur, gbuf, ne, B);
    k_build     <<<B, 1024, 0, stream>>>(gbuf, gcur, off, offend, dinv, csr, n, B);

    k_linear1   <<<256, 256, 0, stream>>>(xraw, w1raw, flags, dinv, h1s, n);
    k_aggA      <<<(n + 15) / 16, 256, 0, stream>>>(off, offend, csr, dinv, h1s, b1raw, flags, actb, n);
    k_linear2   <<<256, 256, 0, stream>>>(actb, w2raw, flags, dinv, h2s, n);
    k_aggB      <<<(n + 63) / 64, 256, 0, stream>>>(off, offend, csr, dinv, h2s, b2raw, flags, d_out, n);
}

// Round 12
// 202.054 us; speedup vs baseline: 1.5425x; 1.0446x over previous
//
#include <hip/hip_runtime.h>
#include <hip/hip_bf16.h>

// GCN 2-layer. Bucketized padded-CSR build, pre-scaled bf16 intermediates
// (h1s = h1*dinv => per-edge work = gather+add), MFMA linear1, and linear2 FUSED
// into aggA (LDS act tile + per-block 16x16x32 MFMA by wave 0 -> h2s directly).
// flags[0]=1 if floats bf16 else fp32; flags[1]=1 if edge_index int64 else int32.

constexpr int D_IN  = 128;
constexpr int D_HID = 64;
constexpr int D_OUT = 16;

constexpr int WSHIFT  = 9;       // bucket = dst >> 9 (512 nodes/bucket)
constexpr int MAXB    = 256;     // max buckets (n <= 131072)
constexpr int BCAP    = 12288;   // gbuf bucket capacity (mean ~8163 at E/N=16)
constexpr int CSRCAP  = 16384;   // csr bucket region (BCAP + 512*8 padding)
constexpr int BIN_CAP = 48;      // LDS bin cap per bucket per chunk (mean ~21)
constexpr int CHUNK   = 4096;

typedef __attribute__((ext_vector_type(8))) short bf16x8;
typedef __attribute__((ext_vector_type(4))) float f32x4;

__device__ inline float bflo(unsigned u){ return __uint_as_float(u << 16); }
__device__ inline float bfhi(unsigned u){ return __uint_as_float(u & 0xffff0000u); }
__device__ inline unsigned f2bu(float f){
    __hip_bfloat16 h = __float2bfloat16(f);
    return (unsigned)*reinterpret_cast<unsigned short*>(&h);
}
__device__ inline float sigf(float x){ return 1.0f / (1.0f + __expf(-x)); }

// ---------------- phase 1: bucketize edges by dst>>9 + on-device dtype detect ----------------
__global__ __launch_bounds__(256) void k_bucketize(
    const int* __restrict__ ei, const unsigned* __restrict__ xraw,
    int* __restrict__ flags, unsigned* __restrict__ gcur,
    unsigned* __restrict__ gbuf, int ne, int B)
{
    __shared__ unsigned bcnt[MAXB];
    __shared__ unsigned bbase[MAXB];
    __shared__ unsigned bins[MAXB * BIN_CAP];   // 49 KB
    __shared__ int s_i64;

    const int t = threadIdx.x, lane = t & 63, wv = t >> 6;
    const int e0 = blockIdx.x * CHUNK;

    if (t < MAXB) bcnt[t] = 0u;
    if (wv == 0){
        int w = ei[2 * lane + 1];
        unsigned long long m = __ballot(w == 0);
        if (lane == 0) s_i64 = (__popcll(m) > 48) ? 1 : 0;
        if (blockIdx.x == 0){
            unsigned u = xraw[lane];
            unsigned h0 = u & 0xffffu, h1 = u >> 16;
            unsigned ex0 = (h0 >> 7) & 0xffu, ex1 = (h1 >> 7) & 0xffu;
            bool bad0 = !((h0 & 0x7fffu) == 0 || (ex0 >= 97 && ex0 <= 157));
            bool bad1 = !((h1 & 0x7fffu) == 0 || (ex1 >= 97 && ex1 <= 157));
            unsigned long long m0 = __ballot(bad0);
            unsigned long long m1 = __ballot(bad1);
            if (lane == 0){
                int bad = __popcll(m0) + __popcll(m1);
                flags[0] = (bad > 8) ? 0 : 1;
                flags[1] = s_i64;
            }
        }
    }
    __syncthreads();
    const int i64 = s_i64;
    const bool vec = ((ne & 1) == 0);

    #pragma unroll
    for (int k = 0; k < CHUNK / 512; ++k){
        int e = e0 + k * 512 + 2 * t;
        int s0, d0, s1, d1;
        int cntE = 0;
        if (vec && e < ne){
            if (i64){
                int4 sp = *(const int4*)&ei[2 * e];
                int4 dp = *(const int4*)&ei[2 * (ne + e)];
                s0 = sp.x; s1 = sp.z; d0 = dp.x; d1 = dp.z;
            } else {
                int2 sp = *(const int2*)&ei[e];
                int2 dp = *(const int2*)&ei[ne + e];
                s0 = sp.x; s1 = sp.y; d0 = dp.x; d1 = dp.y;
            }
            cntE = 2;
        } else {
            if (e < ne){
                if (i64){ s0 = ei[2*e]; d0 = ei[2*(ne+e)]; }
                else    { s0 = ei[e];   d0 = ei[ne+e]; }
                cntE = 1;
                if (e + 1 < ne){
                    if (i64){ s1 = ei[2*(e+1)]; d1 = ei[2*(ne+e+1)]; }
                    else    { s1 = ei[e+1];     d1 = ei[ne+e+1]; }
                    cntE = 2;
                }
            }
        }
        #pragma unroll
        for (int j = 0; j < 2; ++j){
            if (j < cntE){
                int s = j ? s1 : s0, d = j ? d1 : d0;
                int b = d >> WSHIFT;
                unsigned v = ((unsigned)s << WSHIFT) | ((unsigned)d & ((1u << WSHIFT) - 1));
                unsigned p = atomicAdd(&bcnt[b], 1u);
                if (p < (unsigned)BIN_CAP){
                    bins[b * BIN_CAP + p] = v;
                } else {
                    unsigned g = atomicAdd(&gcur[b], 1u);
                    gbuf[(size_t)b * BCAP + g] = v;
                }
            }
        }
    }
    __syncthreads();

    if (t < B){
        unsigned c = min(bcnt[t], (unsigned)BIN_CAP);
        bbase[t] = atomicAdd(&gcur[t], c);
    }
    __syncthreads();

    for (int b = wv; b < B; b += 4){
        unsigned c = min(bcnt[b], (unsigned)BIN_CAP);
        for (unsigned o = lane; o < c; o += 64)
            gbuf[(size_t)b * BCAP + bbase[b] + o] = bins[b * BIN_CAP + o];
    }
}

// ---------------- phase 2: per-bucket hist + scan + PADDED csr fill ----------------
__global__ __launch_bounds__(1024) void k_build(
    const unsigned* __restrict__ gbuf, const unsigned* __restrict__ gcnt,
    unsigned* __restrict__ off, unsigned* __restrict__ offend,
    float* __restrict__ dinv, int* __restrict__ csr, int n, int B)
{
    __shared__ unsigned hist[512];
    __shared__ unsigned offl[512];
    __shared__ unsigned wsums[8];

    const int t = threadIdx.x, lane = t & 63, wv = t >> 6;
    const int b = blockIdx.x;
    const int base = b << WSHIFT;
    const int nodes = min(512, n - base);
    const unsigned bb = (unsigned)b * CSRCAP;

    if (t < 512) hist[t] = 0u;
    __syncthreads();
    const unsigned cnt = gcnt[b];
    const unsigned* mybuf = gbuf + (size_t)b * BCAP;

    for (unsigned i = t; i < cnt; i += 1024)
        atomicAdd(&hist[mybuf[i] & ((1u << WSHIFT) - 1)], 1u);
    __syncthreads();

    unsigned v = 0, p = 0, x = 0;
    if (t < 512){
        v = hist[t];
        p = (v + 7u) & ~7u;
        x = p;
        #pragma unroll
        for (int o = 1; o < 64; o <<= 1){
            unsigned y = __shfl_up(x, o, 64);
            if (lane >= o) x += y;
        }
        if (lane == 63) wsums[wv] = x;
    }
    __syncthreads();
    if (t == 0){
        unsigned run = 0;
        #pragma unroll
        for (int w = 0; w < 8; ++w){ unsigned tv = wsums[w]; wsums[w] = run; run += tv; }
    }
    __syncthreads();
    if (t < 512) offl[t] = x - p + wsums[wv];
    __syncthreads();

    if (t < nodes){
        off[base + t]    = bb + offl[t];
        offend[base + t] = bb + offl[t] + p;
        dinv[base + t]   = rsqrtf(1.0f + (float)v);
    }
    __syncthreads();

    if (t < 512) hist[t] = offl[t];
    __syncthreads();

    for (unsigned i = t; i < cnt; i += 1024){
        unsigned rec = mybuf[i];
        unsigned pos = atomicAdd(&hist[rec & ((1u << WSHIFT) - 1)], 1u);
        csr[bb + pos] = (int)(rec >> WSHIFT);
    }
    __syncthreads();

    if (t < nodes){
        unsigned s = offl[t] + v, e2 = offl[t] + p;
        for (unsigned j = s; j < e2; ++j) csr[bb + j] = n;
    }
}

// ---------------- linear 1 (MFMA): h1s(bf16) = (x @ W1) * dinv[node]; row n = 0 ----------------
__global__ __launch_bounds__(256) void k_linear1(
    const unsigned* __restrict__ xraw, const unsigned* __restrict__ w1raw,
    const int* __restrict__ flags, const float* __restrict__ dinv,
    unsigned short* __restrict__ h1s, int n)
{
    const int lane = threadIdx.x & 63;
    const int wv   = threadIdx.x >> 6;
    const int m = lane & 15, q = lane >> 4;
    const int isBf16 = flags[0];

    if (blockIdx.x == 0 && threadIdx.x < 16)
        ((uint2*)(h1s + (size_t)n * D_HID))[threadIdx.x] = make_uint2(0u, 0u);

    bf16x8 bfr[4][4];
    if (isBf16){
        const unsigned short* w = (const unsigned short*)w1raw;
        #pragma unroll
        for (int kc = 0; kc < 4; ++kc)
            #pragma unroll
            for (int ct = 0; ct < 4; ++ct)
                #pragma unroll
                for (int j = 0; j < 8; ++j)
                    bfr[kc][ct][j] = (short)w[(kc*32 + q*8 + j) * D_HID + ct*16 + m];
    } else {
        const float* w = (const float*)w1raw;
        #pragma unroll
        for (int kc = 0; kc < 4; ++kc)
            #pragma unroll
            for (int ct = 0; ct < 4; ++ct)
                #pragma unroll
                for (int j = 0; j < 8; ++j)
                    bfr[kc][ct][j] = (short)f2bu(w[(kc*32 + q*8 + j) * D_HID + ct*16 + m]);
    }

    const int ntiles = (n + 15) >> 4;
    for (int tile = blockIdx.x * 4 + wv; tile < ntiles; tile += gridDim.x * 4){
        const int node0 = tile << 4;
        int arow = node0 + m; if (arow >= n) arow = n - 1;
        f32x4 ac0 = {0,0,0,0}, ac1 = {0,0,0,0}, ac2 = {0,0,0,0}, ac3 = {0,0,0,0};
        #pragma unroll
        for (int kc = 0; kc < 4; ++kc){
            bf16x8 a;
            if (isBf16){
                uint4 u = *(const uint4*)((const unsigned short*)xraw + (size_t)arow * D_IN + kc*32 + q*8);
                a = *reinterpret_cast<bf16x8*>(&u);
            } else {
                const float* xp = (const float*)xraw + (size_t)arow * D_IN + kc*32 + q*8;
                float4 f0 = *(const float4*)xp;
                float4 f1 = *(const float4*)(xp + 4);
                a[0]=(short)f2bu(f0.x); a[1]=(short)f2bu(f0.y); a[2]=(short)f2bu(f0.z); a[3]=(short)f2bu(f0.w);
                a[4]=(short)f2bu(f1.x); a[5]=(short)f2bu(f1.y); a[6]=(short)f2bu(f1.z); a[7]=(short)f2bu(f1.w);
            }
            ac0 = __builtin_amdgcn_mfma_f32_16x16x32_bf16(a, bfr[kc][0], ac0, 0, 0, 0);
            ac1 = __builtin_amdgcn_mfma_f32_16x16x32_bf16(a, bfr[kc][1], ac1, 0, 0, 0);
            ac2 = __builtin_amdgcn_mfma_f32_16x16x32_bf16(a, bfr[kc][2], ac2, 0, 0, 0);
            ac3 = __builtin_amdgcn_mfma_f32_16x16x32_bf16(a, bfr[kc][3], ac3, 0, 0, 0);
        }
        #pragma unroll
        for (int i = 0; i < 4; ++i){
            int nr = node0 + q*4 + i;
            if (nr < n){
                float di = dinv[nr];
                unsigned short* o = h1s + (size_t)nr * D_HID + m;
                o[0]  = (unsigned short)f2bu(ac0[i] * di);
                o[16] = (unsigned short)f2bu(ac1[i] * di);
                o[32] = (unsigned short)f2bu(ac2[i] * di);
                o[48] = (unsigned short)f2bu(ac3[i] * di);
            }
        }
    }
}

// ---------------- aggA + fused linear2 ----------------
// Block = 16 dsts (4 waves x 4). Phase 1: CSR aggregate + bias + sigmoid -> act tile
// in LDS. Phase 2: wave 0 runs h2s = (act @ W2)*dinv via two 16x16x32 MFMAs.
__global__ __launch_bounds__(256) void k_aggA(
    const unsigned* __restrict__ off, const unsigned* __restrict__ offend,
    const int* __restrict__ csr_src,
    const float* __restrict__ dinv, const unsigned short* __restrict__ h1s,
    const unsigned* __restrict__ b1raw, const unsigned* __restrict__ w2raw,
    const int* __restrict__ flags,
    unsigned short* __restrict__ h2s, int n)
{
    __shared__ unsigned short act_s[16][72];   // 16-node act tile, padded

    const int lane = threadIdx.x & 63;
    const int wv   = threadIdx.x >> 6;
    const int grp  = lane >> 4;            // dst within wave (0..3)
    const int f    = lane & 15;            // uint2 index within 64-feature row
    const int dl   = wv * 4 + grp;         // dst within block (0..15)
    const int d    = blockIdx.x * 16 + dl;
    const int isBf16 = flags[0];

    // W2 B-fragments (only wave 0 uses them)
    bf16x8 w2f[2];
    if (wv == 0){
        const int m0 = lane & 15, q0 = lane >> 4;
        if (isBf16){
            const unsigned short* w = (const unsigned short*)w2raw;
            #pragma unroll
            for (int kc = 0; kc < 2; ++kc)
                #pragma unroll
                for (int j = 0; j < 8; ++j)
                    w2f[kc][j] = (short)w[(kc*32 + q0*8 + j) * D_OUT + m0];
        } else {
            const float* w = (const float*)w2raw;
            #pragma unroll
            for (int kc = 0; kc < 2; ++kc)
                #pragma unroll
                for (int j = 0; j < 8; ++j)
                    w2f[kc][j] = (short)f2bu(w[(kc*32 + q0*8 + j) * D_OUT + m0]);
        }
        if (blockIdx.x == 0 && lane < 4)   // sentinel zero row for aggB
            ((uint2*)(h2s + (size_t)n * D_OUT))[lane] = make_uint2(0u, 0u);
    }

    if (d < n){
        const int beg = (int)off[d], end = (int)offend[d];
        float a0=0.f, a1=0.f, a2=0.f, a3=0.f;
        for (int i = beg; i < end; i += 8){
            uint4 cA = *(const uint4*)&csr_src[i];
            uint4 cB = *(const uint4*)&csr_src[i + 4];
            uint2 u0 = *(const uint2*)&h1s[(size_t)(unsigned)cA.x * D_HID + f * 4];
            uint2 u1 = *(const uint2*)&h1s[(size_t)(unsigned)cA.y * D_HID + f * 4];
            uint2 u2 = *(const uint2*)&h1s[(size_t)(unsigned)cA.z * D_HID + f * 4];
            uint2 u3 = *(const uint2*)&h1s[(size_t)(unsigned)cA.w * D_HID + f * 4];
            uint2 u4 = *(const uint2*)&h1s[(size_t)(unsigned)cB.x * D_HID + f * 4];
            uint2 u5 = *(const uint2*)&h1s[(size_t)(unsigned)cB.y * D_HID + f * 4];
            uint2 u6 = *(const uint2*)&h1s[(size_t)(unsigned)cB.z * D_HID + f * 4];
            uint2 u7 = *(const uint2*)&h1s[(size_t)(unsigned)cB.w * D_HID + f * 4];
            a0 += bflo(u0.x) + bflo(u1.x) + bflo(u2.x) + bflo(u3.x)
                + bflo(u4.x) + bflo(u5.x) + bflo(u6.x) + bflo(u7.x);
            a1 += bfhi(u0.x) + bfhi(u1.x) + bfhi(u2.x) + bfhi(u3.x)
                + bfhi(u4.x) + bfhi(u5.x) + bfhi(u6.x) + bfhi(u7.x);
            a2 += bflo(u0.y) + bflo(u1.y) + bflo(u2.y) + bflo(u3.y)
                + bflo(u4.y) + bflo(u5.y) + bflo(u6.y) + bflo(u7.y);
            a3 += bfhi(u0.y) + bfhi(u1.y) + bfhi(u2.y) + bfhi(u3.y)
                + bfhi(u4.y) + bfhi(u5.y) + bfhi(u6.y) + bfhi(u7.y);
        }
        uint2 su = *(const uint2*)&h1s[(size_t)d * D_HID + f * 4];
        a0 += bflo(su.x); a1 += bfhi(su.x);
        a2 += bflo(su.y); a3 += bfhi(su.y);
        const float dd = dinv[d];
        float b0, b1v, b2v, b3v;
        if (isBf16){
            uint2 bu = ((const uint2*)b1raw)[f];
            b0 = bflo(bu.x); b1v = bfhi(bu.x); b2v = bflo(bu.y); b3v = bfhi(bu.y);
        } else {
            float4 bb = ((const float4*)b1raw)[f];
            b0 = bb.x; b1v = bb.y; b2v = bb.z; b3v = bb.w;
        }
        act_s[dl][f*4+0] = (unsigned short)f2bu(sigf(fmaf(a0, dd, b0)));
        act_s[dl][f*4+1] = (unsigned short)f2bu(sigf(fmaf(a1, dd, b1v)));
        act_s[dl][f*4+2] = (unsigned short)f2bu(sigf(fmaf(a2, dd, b2v)));
        act_s[dl][f*4+3] = (unsigned short)f2bu(sigf(fmaf(a3, dd, b3v)));
    } else {
        #pragma unroll
        for (int j = 0; j < 4; ++j) act_s[dl][f*4+j] = 0;
    }
    __syncthreads();

    // phase 2: wave 0 computes h2s tile = (act @ W2) * dinv
    if (wv == 0){
        const int m0 = lane & 15, q0 = lane >> 4;
        f32x4 acc = {0,0,0,0};
        #pragma unroll
        for (int kc = 0; kc < 2; ++kc){
            bf16x8 a;
            #pragma unroll
            for (int j = 0; j < 8; ++j)
                a[j] = (short)act_s[m0][kc*32 + q0*8 + j];
            acc = __builtin_amdgcn_mfma_f32_16x16x32_bf16(a, w2f[kc], acc, 0, 0, 0);
        }
        #pragma unroll
        for (int i = 0; i < 4; ++i){
            int nr = blockIdx.x * 16 + q0*4 + i;
            if (nr < n)
                h2s[(size_t)nr * D_OUT + m0] = (unsigned short)f2bu(acc[i] * dinv[nr]);
        }
    }
}

// ---------------- aggB: 16 dst/wave, 4 lanes/dst, tail-free unroll x8 ----------------
__global__ __launch_bounds__(256) void k_aggB(
    const unsigned* __restrict__ off, const unsigned* __restrict__ offend,
    const int* __restrict__ csr_src,
    const float* __restrict__ dinv, const unsigned short* __restrict__ h2s,
    const unsigned* __restrict__ b2raw, const int* __restrict__ flags,
    void* __restrict__ out, int n)
{
    const int lane = threadIdx.x & 63;
    const int wv   = threadIdx.x >> 6;
    const int grp  = lane >> 2;            // dst within wave (0..15)
    const int f    = lane & 3;             // uint2 index within 16-feature row
    const int d    = (blockIdx.x * 4 + wv) * 16 + grp;
    const int isBf16 = flags[0];
    if (d >= n) return;

    const int beg = (int)off[d], end = (int)offend[d];
    float a0=0.f, a1=0.f, a2=0.f, a3=0.f;
    for (int i = beg; i < end; i += 8){
        uint4 cA = *(const uint4*)&csr_src[i];
        uint4 cB = *(const uint4*)&csr_src[i + 4];
        uint2 u0 = *(const uint2*)&h2s[(size_t)(unsigned)cA.x * D_OUT + f * 4];
        uint2 u1 = *(const uint2*)&h2s[(size_t)(unsigned)cA.y * D_OUT + f * 4];
        uint2 u2 = *(const uint2*)&h2s[(size_t)(unsigned)cA.z * D_OUT + f * 4];
        uint2 u3 = *(const uint2*)&h2s[(size_t)(unsigned)cA.w * D_OUT + f * 4];
        uint2 u4 = *(const uint2*)&h2s[(size_t)(unsigned)cB.x * D_OUT + f * 4];
        uint2 u5 = *(const uint2*)&h2s[(size_t)(unsigned)cB.y * D_OUT + f * 4];
        uint2 u6 = *(const uint2*)&h2s[(size_t)(unsigned)cB.z * D_OUT + f * 4];
        uint2 u7 = *(const uint2*)&h2s[(size_t)(unsigned)cB.w * D_OUT + f * 4];
        a0 += bflo(u0.x) + bflo(u1.x) + bflo(u2.x) + bflo(u3.x)
            + bflo(u4.x) + bflo(u5.x) + bflo(u6.x) + bflo(u7.x);
        a1 += bfhi(u0.x) + bfhi(u1.x) + bfhi(u2.x) + bfhi(u3.x)
            + bfhi(u4.x) + bfhi(u5.x) + bfhi(u6.x) + bfhi(u7.x);
        a2 += bflo(u0.y) + bflo(u1.y) + bflo(u2.y) + bflo(u3.y)
            + bflo(u4.y) + bflo(u5.y) + bflo(u6.y) + bflo(u7.y);
        a3 += bfhi(u0.y) + bfhi(u1.y) + bfhi(u2.y) + bfhi(u3.y)
            + bfhi(u4.y) + bfhi(u5.y) + bfhi(u6.y) + bfhi(u7.y);
    }
    uint2 su = *(const uint2*)&h2s[(size_t)d * D_OUT + f * 4];
    a0 += bflo(su.x); a1 += bfhi(su.x);
    a2 += bflo(su.y); a3 += bfhi(su.y);
    const float dd = dinv[d];
    float b0, b1v, b2v, b3v;
    if (isBf16){
        uint2 bu = ((const uint2*)b2raw)[f];
        b0 = bflo(bu.x); b1v = bfhi(bu.x); b2v = bflo(bu.y); b3v = bfhi(bu.y);
    } else {
        float4 bb = ((const float4*)b2raw)[f];
        b0 = bb.x; b1v = bb.y; b2v = bb.z; b3v = bb.w;
    }
    a0 = fmaf(a0, dd, b0); a1 = fmaf(a1, dd, b1v);
    a2 = fmaf(a2, dd, b2v); a3 = fmaf(a3, dd, b3v);
    float m = fmaxf(fmaxf(a0, a1), fmaxf(a2, a3));
    m = fmaxf(m, __shfl_xor(m, 1, 4));
    m = fmaxf(m, __shfl_xor(m, 2, 4));
    float s = __expf(a0 - m) + __expf(a1 - m) + __expf(a2 - m) + __expf(a3 - m);
    s += __shfl_xor(s, 1, 4);
    s += __shfl_xor(s, 2, 4);
    float ls = m + __logf(s);
    if (isBf16){
        uint2 pk;
        pk.x = f2bu(a0 - ls) | (f2bu(a1 - ls) << 16);
        pk.y = f2bu(a2 - ls) | (f2bu(a3 - ls) << 16);
        *(uint2*)((__hip_bfloat16*)out + (size_t)d * D_OUT + f * 4) = pk;
    } else {
        float4 o4 = make_float4(a0 - ls, a1 - ls, a2 - ls, a3 - ls);
        *(float4*)((float*)out + (size_t)d * D_OUT + f * 4) = o4;
    }
}

extern "C" void kernel_launch(void* const* d_in, const int* in_sizes, int n_in,
                              void* d_out, int out_size, void* d_ws, size_t ws_size,
                              hipStream_t stream)
{
    const unsigned* xraw  = (const unsigned*)d_in[0];
    const int*      ei    = (const int*)d_in[1];
    const unsigned* w1raw = (const unsigned*)d_in[2];
    const unsigned* b1raw = (const unsigned*)d_in[3];
    const unsigned* w2raw = (const unsigned*)d_in[4];
    const unsigned* b2raw = (const unsigned*)d_in[5];

    const int n  = in_sizes[0] / D_IN;   // 100000
    const int ne = in_sizes[1] / 2;      // 1600000
    const int B  = (n + ((1 << WSHIFT) - 1)) >> WSHIFT;   // 196 buckets

    // ws layout (4B words):
    // flags[64] | gcur[256] | dinv[nAl] | off[nAl] | offend[nAl] | csr[MAXB*CSRCAP]
    //   | gbuf[MAXB*BCAP] | h1s[(n+16)*64 bf16] | h2s[(n+16)*16 bf16]
    size_t nAl = ((size_t)n + 255) & ~(size_t)255;
    int*            flags  = (int*)d_ws;
    unsigned*       gcur   = (unsigned*)d_ws + 64;
    float*          dinv   = (float*)(gcur + 256);
    unsigned*       off    = (unsigned*)(dinv + nAl);
    unsigned*       offend = off + nAl;
    int*            csr    = (int*)(offend + nAl);
    unsigned*       gbuf   = (unsigned*)(csr + (size_t)MAXB * CSRCAP);
    unsigned short* h1s    = (unsigned short*)(gbuf + (size_t)MAXB * BCAP);
    unsigned short* h2s    = h1s + (size_t)(n + 16) * D_HID;

    const int nchunk = (ne + CHUNK - 1) / CHUNK;

    hipMemsetAsync(gcur, 0, MAXB * sizeof(unsigned), stream);
    k_bucketize <<<nchunk, 256, 0, stream>>>(ei, xraw, flags, gcur, gbuf, ne, B);
    k_build     <<<B, 1024, 0, stream>>>(gbuf, gcur, off, offend, dinv, csr, n, B);

    k_linear1   <<<256, 256, 0, stream>>>(xraw, w1raw, flags, dinv, h1s, n);
    k_aggA      <<<(n + 15) / 16, 256, 0, stream>>>(off, offend, csr, dinv, h1s, b1raw, w2raw, flags, h2s, n);
    k_aggB      <<<(n + 63) / 64, 256, 0, stream>>>(off, offend, csr, dinv, h2s, b2raw, flags, d_out, n);
}

// Round 13
// 194.988 us; speedup vs baseline: 1.5984x; 1.0362x over previous
//
#include <hip/hip_runtime.h>
#include <hip/hip_bf16.h>

// GCN 2-layer. Bucketized padded-CSR build, pre-scaled bf16 intermediates
// (h1s = h1*dinv => per-edge work = gather+add), MFMA linear1 (grid-saturated:
// 1 tile/wave), linear2 FUSED into aggA (LDS act tile + wave-0 MFMA -> h2s).
// flags[0]=1 if floats bf16 else fp32; flags[1]=1 if edge_index int64 else int32.

constexpr int D_IN  = 128;
constexpr int D_HID = 64;
constexpr int D_OUT = 16;

constexpr int WSHIFT  = 9;       // bucket = dst >> 9 (512 nodes/bucket)
constexpr int MAXB    = 256;     // max buckets (n <= 131072)
constexpr int BCAP    = 12288;   // gbuf bucket capacity (mean ~8163 at E/N=16)
constexpr int CSRCAP  = 16384;   // csr bucket region (BCAP + 512*8 padding)
constexpr int BIN_CAP = 48;      // LDS bin cap per bucket per chunk (mean ~21)
constexpr int CHUNK   = 4096;

typedef __attribute__((ext_vector_type(8))) short bf16x8;
typedef __attribute__((ext_vector_type(4))) float f32x4;

__device__ inline float bflo(unsigned u){ return __uint_as_float(u << 16); }
__device__ inline float bfhi(unsigned u){ return __uint_as_float(u & 0xffff0000u); }
__device__ inline unsigned f2bu(float f){
    __hip_bfloat16 h = __float2bfloat16(f);
    return (unsigned)*reinterpret_cast<unsigned short*>(&h);
}
__device__ inline float sigf(float x){ return 1.0f / (1.0f + __expf(-x)); }

// ---------------- phase 1: bucketize edges by dst>>9 + on-device dtype detect ----------------
__global__ __launch_bounds__(256) void k_bucketize(
    const int* __restrict__ ei, const unsigned* __restrict__ xraw,
    int* __restrict__ flags, unsigned* __restrict__ gcur,
    unsigned* __restrict__ gbuf, int ne, int B)
{
    __shared__ unsigned bcnt[MAXB];
    __shared__ unsigned bbase[MAXB];
    __shared__ unsigned bins[MAXB * BIN_CAP];   // 49 KB
    __shared__ int s_i64;

    const int t = threadIdx.x, lane = t & 63, wv = t >> 6;
    const int e0 = blockIdx.x * CHUNK;

    if (t < MAXB) bcnt[t] = 0u;
    if (wv == 0){
        int w = ei[2 * lane + 1];
        unsigned long long m = __ballot(w == 0);
        if (lane == 0) s_i64 = (__popcll(m) > 48) ? 1 : 0;
        if (blockIdx.x == 0){
            unsigned u = xraw[lane];
            unsigned h0 = u & 0xffffu, h1 = u >> 16;
            unsigned ex0 = (h0 >> 7) & 0xffu, ex1 = (h1 >> 7) & 0xffu;
            bool bad0 = !((h0 & 0x7fffu) == 0 || (ex0 >= 97 && ex0 <= 157));
            bool bad1 = !((h1 & 0x7fffu) == 0 || (ex1 >= 97 && ex1 <= 157));
            unsigned long long m0 = __ballot(bad0);
            unsigned long long m1 = __ballot(bad1);
            if (lane == 0){
                int bad = __popcll(m0) + __popcll(m1);
                flags[0] = (bad > 8) ? 0 : 1;
                flags[1] = s_i64;
            }
        }
    }
    __syncthreads();
    const int i64 = s_i64;
    const bool vec = ((ne & 1) == 0);

    #pragma unroll
    for (int k = 0; k < CHUNK / 512; ++k){
        int e = e0 + k * 512 + 2 * t;
        int s0, d0, s1, d1;
        int cntE = 0;
        if (vec && e < ne){
            if (i64){
                int4 sp = *(const int4*)&ei[2 * e];
                int4 dp = *(const int4*)&ei[2 * (ne + e)];
                s0 = sp.x; s1 = sp.z; d0 = dp.x; d1 = dp.z;
            } else {
                int2 sp = *(const int2*)&ei[e];
                int2 dp = *(const int2*)&ei[ne + e];
                s0 = sp.x; s1 = sp.y; d0 = dp.x; d1 = dp.y;
            }
            cntE = 2;
        } else {
            if (e < ne){
                if (i64){ s0 = ei[2*e]; d0 = ei[2*(ne+e)]; }
                else    { s0 = ei[e];   d0 = ei[ne+e]; }
                cntE = 1;
                if (e + 1 < ne){
                    if (i64){ s1 = ei[2*(e+1)]; d1 = ei[2*(ne+e+1)]; }
                    else    { s1 = ei[e+1];     d1 = ei[ne+e+1]; }
                    cntE = 2;
                }
            }
        }
        #pragma unroll
        for (int j = 0; j < 2; ++j){
            if (j < cntE){
                int s = j ? s1 : s0, d = j ? d1 : d0;
                int b = d >> WSHIFT;
                unsigned v = ((unsigned)s << WSHIFT) | ((unsigned)d & ((1u << WSHIFT) - 1));
                unsigned p = atomicAdd(&bcnt[b], 1u);
                if (p < (unsigned)BIN_CAP){
                    bins[b * BIN_CAP + p] = v;
                } else {
                    unsigned g = atomicAdd(&gcur[b], 1u);
                    gbuf[(size_t)b * BCAP + g] = v;
                }
            }
        }
    }
    __syncthreads();

    if (t < B){
        unsigned c = min(bcnt[t], (unsigned)BIN_CAP);
        bbase[t] = atomicAdd(&gcur[t], c);
    }
    __syncthreads();

    for (int b = wv; b < B; b += 4){
        unsigned c = min(bcnt[b], (unsigned)BIN_CAP);
        for (unsigned o = lane; o < c; o += 64)
            gbuf[(size_t)b * BCAP + bbase[b] + o] = bins[b * BIN_CAP + o];
    }
}

// ---------------- phase 2: per-bucket hist + scan + PADDED csr fill ----------------
__global__ __launch_bounds__(1024) void k_build(
    const unsigned* __restrict__ gbuf, const unsigned* __restrict__ gcnt,
    unsigned* __restrict__ off, unsigned* __restrict__ offend,
    float* __restrict__ dinv, int* __restrict__ csr, int n, int B)
{
    __shared__ unsigned hist[512];
    __shared__ unsigned offl[512];
    __shared__ unsigned wsums[8];

    const int t = threadIdx.x, lane = t & 63, wv = t >> 6;
    const int b = blockIdx.x;
    const int base = b << WSHIFT;
    const int nodes = min(512, n - base);
    const unsigned bb = (unsigned)b * CSRCAP;

    if (t < 512) hist[t] = 0u;
    __syncthreads();
    const unsigned cnt = gcnt[b];
    const unsigned* mybuf = gbuf + (size_t)b * BCAP;

    for (unsigned i = t; i < cnt; i += 1024)
        atomicAdd(&hist[mybuf[i] & ((1u << WSHIFT) - 1)], 1u);
    __syncthreads();

    unsigned v = 0, p = 0, x = 0;
    if (t < 512){
        v = hist[t];
        p = (v + 7u) & ~7u;
        x = p;
        #pragma unroll
        for (int o = 1; o < 64; o <<= 1){
            unsigned y = __shfl_up(x, o, 64);
            if (lane >= o) x += y;
        }
        if (lane == 63) wsums[wv] = x;
    }
    __syncthreads();
    if (t == 0){
        unsigned run = 0;
        #pragma unroll
        for (int w = 0; w < 8; ++w){ unsigned tv = wsums[w]; wsums[w] = run; run += tv; }
    }
    __syncthreads();
    if (t < 512) offl[t] = x - p + wsums[wv];
    __syncthreads();

    if (t < nodes){
        off[base + t]    = bb + offl[t];
        offend[base + t] = bb + offl[t] + p;
        dinv[base + t]   = rsqrtf(1.0f + (float)v);
    }
    __syncthreads();

    if (t < 512) hist[t] = offl[t];
    __syncthreads();

    for (unsigned i = t; i < cnt; i += 1024){
        unsigned rec = mybuf[i];
        unsigned pos = atomicAdd(&hist[rec & ((1u << WSHIFT) - 1)], 1u);
        csr[bb + pos] = (int)(rec >> WSHIFT);
    }
    __syncthreads();

    if (t < nodes){
        unsigned s = offl[t] + v, e2 = offl[t] + p;
        for (unsigned j = s; j < e2; ++j) csr[bb + j] = n;
    }
}

// ---------------- linear 1 (MFMA): h1s(bf16) = (x @ W1) * dinv[node]; row n = 0 ----------------
// Grid-saturated: one 16-node tile per wave.
__global__ __launch_bounds__(256) void k_linear1(
    const unsigned* __restrict__ xraw, const unsigned* __restrict__ w1raw,
    const int* __restrict__ flags, const float* __restrict__ dinv,
    unsigned short* __restrict__ h1s, int n)
{
    const int lane = threadIdx.x & 63;
    const int wv   = threadIdx.x >> 6;
    const int m = lane & 15, q = lane >> 4;
    const int isBf16 = flags[0];

    if (blockIdx.x == 0 && threadIdx.x < 16)
        ((uint2*)(h1s + (size_t)n * D_HID))[threadIdx.x] = make_uint2(0u, 0u);

    bf16x8 bfr[4][4];
    if (isBf16){
        const unsigned short* w = (const unsigned short*)w1raw;
        #pragma unroll
        for (int kc = 0; kc < 4; ++kc)
            #pragma unroll
            for (int ct = 0; ct < 4; ++ct)
                #pragma unroll
                for (int j = 0; j < 8; ++j)
                    bfr[kc][ct][j] = (short)w[(kc*32 + q*8 + j) * D_HID + ct*16 + m];
    } else {
        const float* w = (const float*)w1raw;
        #pragma unroll
        for (int kc = 0; kc < 4; ++kc)
            #pragma unroll
            for (int ct = 0; ct < 4; ++ct)
                #pragma unroll
                for (int j = 0; j < 8; ++j)
                    bfr[kc][ct][j] = (short)f2bu(w[(kc*32 + q*8 + j) * D_HID + ct*16 + m]);
    }

    const int ntiles = (n + 15) >> 4;
    for (int tile = blockIdx.x * 4 + wv; tile < ntiles; tile += gridDim.x * 4){
        const int node0 = tile << 4;
        int arow = node0 + m; if (arow >= n) arow = n - 1;
        f32x4 ac0 = {0,0,0,0}, ac1 = {0,0,0,0}, ac2 = {0,0,0,0}, ac3 = {0,0,0,0};
        #pragma unroll
        for (int kc = 0; kc < 4; ++kc){
            bf16x8 a;
            if (isBf16){
                uint4 u = *(const uint4*)((const unsigned short*)xraw + (size_t)arow * D_IN + kc*32 + q*8);
                a = *reinterpret_cast<bf16x8*>(&u);
            } else {
                const float* xp = (const float*)xraw + (size_t)arow * D_IN + kc*32 + q*8;
                float4 f0 = *(const float4*)xp;
                float4 f1 = *(const float4*)(xp + 4);
                a[0]=(short)f2bu(f0.x); a[1]=(short)f2bu(f0.y); a[2]=(short)f2bu(f0.z); a[3]=(short)f2bu(f0.w);
                a[4]=(short)f2bu(f1.x); a[5]=(short)f2bu(f1.y); a[6]=(short)f2bu(f1.z); a[7]=(short)f2bu(f1.w);
            }
            ac0 = __builtin_amdgcn_mfma_f32_16x16x32_bf16(a, bfr[kc][0], ac0, 0, 0, 0);
            ac1 = __builtin_amdgcn_mfma_f32_16x16x32_bf16(a, bfr[kc][1], ac1, 0, 0, 0);
            ac2 = __builtin_amdgcn_mfma_f32_16x16x32_bf16(a, bfr[kc][2], ac2, 0, 0, 0);
            ac3 = __builtin_amdgcn_mfma_f32_16x16x32_bf16(a, bfr[kc][3], ac3, 0, 0, 0);
        }
        #pragma unroll
        for (int i = 0; i < 4; ++i){
            int nr = node0 + q*4 + i;
            if (nr < n){
                float di = dinv[nr];
                unsigned short* o = h1s + (size_t)nr * D_HID + m;
                o[0]  = (unsigned short)f2bu(ac0[i] * di);
                o[16] = (unsigned short)f2bu(ac1[i] * di);
                o[32] = (unsigned short)f2bu(ac2[i] * di);
                o[48] = (unsigned short)f2bu(ac3[i] * di);
            }
        }
    }
}

// ---------------- aggA + fused linear2 ----------------
__global__ __launch_bounds__(256) void k_aggA(
    const unsigned* __restrict__ off, const unsigned* __restrict__ offend,
    const int* __restrict__ csr_src,
    const float* __restrict__ dinv, const unsigned short* __restrict__ h1s,
    const unsigned* __restrict__ b1raw, const unsigned* __restrict__ w2raw,
    const int* __restrict__ flags,
    unsigned short* __restrict__ h2s, int n)
{
    __shared__ unsigned short act_s[16][72];   // 16-node act tile, padded

    const int lane = threadIdx.x & 63;
    const int wv   = threadIdx.x >> 6;
    const int grp  = lane >> 4;            // dst within wave (0..3)
    const int f    = lane & 15;            // uint2 index within 64-feature row
    const int dl   = wv * 4 + grp;         // dst within block (0..15)
    const int d    = blockIdx.x * 16 + dl;
    const int isBf16 = flags[0];

    bf16x8 w2f[2];
    if (wv == 0){
        const int m0 = lane & 15, q0 = lane >> 4;
        if (isBf16){
            const unsigned short* w = (const unsigned short*)w2raw;
            #pragma unroll
            for (int kc = 0; kc < 2; ++kc)
                #pragma unroll
                for (int j = 0; j < 8; ++j)
                    w2f[kc][j] = (short)w[(kc*32 + q0*8 + j) * D_OUT + m0];
        } else {
            const float* w = (const float*)w2raw;
            #pragma unroll
            for (int kc = 0; kc < 2; ++kc)
                #pragma unroll
                for (int j = 0; j < 8; ++j)
                    w2f[kc][j] = (short)f2bu(w[(kc*32 + q0*8 + j) * D_OUT + m0]);
        }
        if (blockIdx.x == 0 && lane < 4)
            ((uint2*)(h2s + (size_t)n * D_OUT))[lane] = make_uint2(0u, 0u);
    }

    if (d < n){
        const int beg = (int)off[d], end = (int)offend[d];
        float a0=0.f, a1=0.f, a2=0.f, a3=0.f;
        for (int i = beg; i < end; i += 8){
            uint4 cA = *(const uint4*)&csr_src[i];
            uint4 cB = *(const uint4*)&csr_src[i + 4];
            uint2 u0 = *(const uint2*)&h1s[(size_t)(unsigned)cA.x * D_HID + f * 4];
            uint2 u1 = *(const uint2*)&h1s[(size_t)(unsigned)cA.y * D_HID + f * 4];
            uint2 u2 = *(const uint2*)&h1s[(size_t)(unsigned)cA.z * D_HID + f * 4];
            uint2 u3 = *(const uint2*)&h1s[(size_t)(unsigned)cA.w * D_HID + f * 4];
            uint2 u4 = *(const uint2*)&h1s[(size_t)(unsigned)cB.x * D_HID + f * 4];
            uint2 u5 = *(const uint2*)&h1s[(size_t)(unsigned)cB.y * D_HID + f * 4];
            uint2 u6 = *(const uint2*)&h1s[(size_t)(unsigned)cB.z * D_HID + f * 4];
            uint2 u7 = *(const uint2*)&h1s[(size_t)(unsigned)cB.w * D_HID + f * 4];
            a0 += bflo(u0.x) + bflo(u1.x) + bflo(u2.x) + bflo(u3.x)
                + bflo(u4.x) + bflo(u5.x) + bflo(u6.x) + bflo(u7.x);
            a1 += bfhi(u0.x) + bfhi(u1.x) + bfhi(u2.x) + bfhi(u3.x)
                + bfhi(u4.x) + bfhi(u5.x) + bfhi(u6.x) + bfhi(u7.x);
            a2 += bflo(u0.y) + bflo(u1.y) + bflo(u2.y) + bflo(u3.y)
                + bflo(u4.y) + bflo(u5.y) + bflo(u6.y) + bflo(u7.y);
            a3 += bfhi(u0.y) + bfhi(u1.y) + bfhi(u2.y) + bfhi(u3.y)
                + bfhi(u4.y) + bfhi(u5.y) + bfhi(u6.y) + bfhi(u7.y);
        }
        uint2 su = *(const uint2*)&h1s[(size_t)d * D_HID + f * 4];
        a0 += bflo(su.x); a1 += bfhi(su.x);
        a2 += bflo(su.y); a3 += bfhi(su.y);
        const float dd = dinv[d];
        float b0, b1v, b2v, b3v;
        if (isBf16){
            uint2 bu = ((const uint2*)b1raw)[f];
            b0 = bflo(bu.x); b1v = bfhi(bu.x); b2v = bflo(bu.y); b3v = bfhi(bu.y);
        } else {
            float4 bb = ((const float4*)b1raw)[f];
            b0 = bb.x; b1v = bb.y; b2v = bb.z; b3v = bb.w;
        }
        act_s[dl][f*4+0] = (unsigned short)f2bu(sigf(fmaf(a0, dd, b0)));
        act_s[dl][f*4+1] = (unsigned short)f2bu(sigf(fmaf(a1, dd, b1v)));
        act_s[dl][f*4+2] = (unsigned short)f2bu(sigf(fmaf(a2, dd, b2v)));
        act_s[dl][f*4+3] = (unsigned short)f2bu(sigf(fmaf(a3, dd, b3v)));
    } else {
        #pragma unroll
        for (int j = 0; j < 4; ++j) act_s[dl][f*4+j] = 0;
    }
    __syncthreads();

    if (wv == 0){
        const int m0 = lane & 15, q0 = lane >> 4;
        f32x4 acc = {0,0,0,0};
        #pragma unroll
        for (int kc = 0; kc < 2; ++kc){
            bf16x8 a;
            #pragma unroll
            for (int j = 0; j < 8; ++j)
                a[j] = (short)act_s[m0][kc*32 + q0*8 + j];
            acc = __builtin_amdgcn_mfma_f32_16x16x32_bf16(a, w2f[kc], acc, 0, 0, 0);
        }
        #pragma unroll
        for (int i = 0; i < 4; ++i){
            int nr = blockIdx.x * 16 + q0*4 + i;
            if (nr < n)
                h2s[(size_t)nr * D_OUT + m0] = (unsigned short)f2bu(acc[i] * dinv[nr]);
        }
    }
}

// ---------------- aggB: 16 dst/wave, 4 lanes/dst, tail-free unroll x8 ----------------
__global__ __launch_bounds__(256) void k_aggB(
    const unsigned* __restrict__ off, const unsigned* __restrict__ offend,
    const int* __restrict__ csr_src,
    const float* __restrict__ dinv, const unsigned short* __restrict__ h2s,
    const unsigned* __restrict__ b2raw, const int* __restrict__ flags,
    void* __restrict__ out, int n)
{
    const int lane = threadIdx.x & 63;
    const int wv   = threadIdx.x >> 6;
    const int grp  = lane >> 2;            // dst within wave (0..15)
    const int f    = lane & 3;             // uint2 index within 16-feature row
    const int d    = (blockIdx.x * 4 + wv) * 16 + grp;
    const int isBf16 = flags[0];
    if (d >= n) return;

    const int beg = (int)off[d], end = (int)offend[d];
    float a0=0.f, a1=0.f, a2=0.f, a3=0.f;
    for (int i = beg; i < end; i += 8){
        uint4 cA = *(const uint4*)&csr_src[i];
        uint4 cB = *(const uint4*)&csr_src[i + 4];
        uint2 u0 = *(const uint2*)&h2s[(size_t)(unsigned)cA.x * D_OUT + f * 4];
        uint2 u1 = *(const uint2*)&h2s[(size_t)(unsigned)cA.y * D_OUT + f * 4];
        uint2 u2 = *(const uint2*)&h2s[(size_t)(unsigned)cA.z * D_OUT + f * 4];
        uint2 u3 = *(const uint2*)&h2s[(size_t)(unsigned)cA.w * D_OUT + f * 4];
        uint2 u4 = *(const uint2*)&h2s[(size_t)(unsigned)cB.x * D_OUT + f * 4];
        uint2 u5 = *(const uint2*)&h2s[(size_t)(unsigned)cB.y * D_OUT + f * 4];
        uint2 u6 = *(const uint2*)&h2s[(size_t)(unsigned)cB.z * D_OUT + f * 4];
        uint2 u7 = *(const uint2*)&h2s[(size_t)(unsigned)cB.w * D_OUT + f * 4];
        a0 += bflo(u0.x) + bflo(u1.x) + bflo(u2.x) + bflo(u3.x)
            + bflo(u4.x) + bflo(u5.x) + bflo(u6.x) + bflo(u7.x);
        a1 += bfhi(u0.x) + bfhi(u1.x) + bfhi(u2.x) + bfhi(u3.x)
            + bfhi(u4.x) + bfhi(u5.x) + bfhi(u6.x) + bfhi(u7.x);
        a2 += bflo(u0.y) + bflo(u1.y) + bflo(u2.y) + bflo(u3.y)
            + bflo(u4.y) + bflo(u5.y) + bflo(u6.y) + bflo(u7.y);
        a3 += bfhi(u0.y) + bfhi(u1.y) + bfhi(u2.y) + bfhi(u3.y)
            + bfhi(u4.y) + bfhi(u5.y) + bfhi(u6.y) + bfhi(u7.y);
    }
    uint2 su = *(const uint2*)&h2s[(size_t)d * D_OUT + f * 4];
    a0 += bflo(su.x); a1 += bfhi(su.x);
    a2 += bflo(su.y); a3 += bfhi(su.y);
    const float dd = dinv[d];
    float b0, b1v, b2v, b3v;
    if (isBf16){
        uint2 bu = ((const uint2*)b2raw)[f];
        b0 = bflo(bu.x); b1v = bfhi(bu.x); b2v = bflo(bu.y); b3v = bfhi(bu.y);
    } else {
        float4 bb = ((const float4*)b2raw)[f];
        b0 = bb.x; b1v = bb.y; b2v = bb.z; b3v = bb.w;
    }
    a0 = fmaf(a0, dd, b0); a1 = fmaf(a1, dd, b1v);
    a2 = fmaf(a2, dd, b2v); a3 = fmaf(a3, dd, b3v);
    float m = fmaxf(fmaxf(a0, a1), fmaxf(a2, a3));
    m = fmaxf(m, __shfl_xor(m, 1, 4));
    m = fmaxf(m, __shfl_xor(m, 2, 4));
    float s = __expf(a0 - m) + __expf(a1 - m) + __expf(a2 - m) + __expf(a3 - m);
    s += __shfl_xor(s, 1, 4);
    s += __shfl_xor(s, 2, 4);
    float ls = m + __logf(s);
    if (isBf16){
        uint2 pk;
        pk.x = f2bu(a0 - ls) | (f2bu(a1 - ls) << 16);
        pk.y = f2bu(a2 - ls) | (f2bu(a3 - ls) << 16);
        *(uint2*)((__hip_bfloat16*)out + (size_t)d * D_OUT + f * 4) = pk;
    } else {
        float4 o4 = make_float4(a0 - ls, a1 - ls, a2 - ls, a3 - ls);
        *(float4*)((float*)out + (size_t)d * D_OUT + f * 4) = o4;
    }
}

extern "C" void kernel_launch(void* const* d_in, const int* in_sizes, int n_in,
                              void* d_out, int out_size, void* d_ws, size_t ws_size,
                              hipStream_t stream)
{
    const unsigned* xraw  = (const unsigned*)d_in[0];
    const int*      ei    = (const int*)d_in[1];
    const unsigned* w1raw = (const unsigned*)d_in[2];
    const unsigned* b1raw = (const unsigned*)d_in[3];
    const unsigned* w2raw = (const unsigned*)d_in[4];
    const unsigned* b2raw = (const unsigned*)d_in[5];

    const int n  = in_sizes[0] / D_IN;   // 100000
    const int ne = in_sizes[1] / 2;      // 1600000
    const int B  = (n + ((1 << WSHIFT) - 1)) >> WSHIFT;   // 196 buckets

    // ws layout (4B words):
    // flags[64] | gcur[256] | dinv[nAl] | off[nAl] | offend[nAl] | csr[MAXB*CSRCAP]
    //   | gbuf[MAXB*BCAP] | h1s[(n+16)*64 bf16] | h2s[(n+16)*16 bf16]
    size_t nAl = ((size_t)n + 255) & ~(size_t)255;
    int*            flags  = (int*)d_ws;
    unsigned*       gcur   = (unsigned*)d_ws + 64;
    float*          dinv   = (float*)(gcur + 256);
    unsigned*       off    = (unsigned*)(dinv + nAl);
    unsigned*       offend = off + nAl;
    int*            csr    = (int*)(offend + nAl);
    unsigned*       gbuf   = (unsigned*)(csr + (size_t)MAXB * CSRCAP);
    unsigned short* h1s    = (unsigned short*)(gbuf + (size_t)MAXB * BCAP);
    unsigned short* h2s    = h1s + (size_t)(n + 16) * D_HID;

    const int nchunk  = (ne + CHUNK - 1) / CHUNK;
    const int ntiles1 = (n + 15) / 16;
    const int grid1   = (ntiles1 + 3) / 4;    // one 16-node tile per wave

    hipMemsetAsync(gcur, 0, MAXB * sizeof(unsigned), stream);
    k_bucketize <<<nchunk, 256, 0, stream>>>(ei, xraw, flags, gcur, gbuf, ne, B);
    k_build     <<<B, 1024, 0, stream>>>(gbuf, gcur, off, offend, dinv, csr, n, B);

    k_linear1   <<<grid1, 256, 0, stream>>>(xraw, w1raw, flags, dinv, h1s, n);
    k_aggA      <<<(n + 15) / 16, 256, 0, stream>>>(off, offend, csr, dinv, h1s, b1raw, w2raw, flags, h2s, n);
    k_aggB      <<<(n + 63) / 64, 256, 0, stream>>>(off, offend, csr, dinv, h2s, b2raw, flags, d_out, n);
}